// Round 10
// baseline (19500.887 us; speedup 1.0000x reference)
//
#include <hip/hip_runtime.h>
#include <hip/hip_bf16.h>

typedef unsigned int u32;
typedef unsigned short u16;
typedef u32 u32x4 __attribute__((ext_vector_type(4)));
typedef float f32x4 __attribute__((ext_vector_type(4)));

// ---------------------------------------------------------------------------
// B=32, N=64, R=256. 32 WGs x 256 threads, 1 batch per WG. Thread t = col t.
// Weights NEVER touch VGPRs: global_load_lds streams 8KB wave-private
// chunk-slices (dbuf, counted vmcnt(8)). ROUND-9 LESSON: any VGPR-routed
// weight stream spills on this toolchain (128-VGPR budget immovable);
// LDS-direct staging removes the failure mode by construction.
//
// Panel image per 32KB chunk (k-quarter cg): byte a: c=a>>7 (col 0..255),
// slot s=(a>>4)&7, j=(a>>1)&7 -> kq = s ^ (c&7) (XOR swizzle, T2), element
// W[cg*64+kq*8+j][c]. Wave w stages bytes [w*8192,+8192) = cols [64w,64w+64)
// == exactly the cols its threads compute -> wave-private, no barriers.
// ---------------------------------------------------------------------------

struct G4 { const float* Bm[4]; const float* bias[4]; float* C[4]; };

__global__ __launch_bounds__(256) void gemm16(const float* __restrict__ A, G4 g) {
  __shared__ float At[16 * 256];
  const int sub = blockIdx.y;
  const float* __restrict__ Bm = g.Bm[sub];
  const float* __restrict__ bias = g.bias[sub];
  float* __restrict__ C = g.C[sub];
  const int r0 = blockIdx.x * 16;
  const int t = threadIdx.x;
#pragma unroll
  for (int j = 0; j < 16; ++j) At[j * 256 + t] = A[(r0 + j) * 256 + t];
  __syncthreads();
  float acc[16];
#pragma unroll
  for (int j = 0; j < 16; ++j) acc[j] = 0.f;
  for (int k = 0; k < 256; ++k) {
    const float bv = Bm[k * 256 + t];
#pragma unroll
    for (int j = 0; j < 16; ++j) acc[j] = fmaf(At[j * 256 + k], bv, acc[j]);
  }
  const float bs = bias[t];
#pragma unroll
  for (int j = 0; j < 16; ++j) C[(r0 + j) * 256 + t] = acc[j] + bs;
}

struct C12 { const float* src[12]; };

__device__ __forceinline__ u16 bfb_(float x) {
  union { __hip_bfloat16 h; u16 u; } c; c.h = __float2bfloat16(x); return c.u;
}

__global__ __launch_bounds__(256) void cvt_panels(C12 c, u16* __restrict__ dst) {
  const int z = blockIdx.y;
  const float* __restrict__ in = c.src[z];
  const int e = blockIdx.x * 256 + threadIdx.x;   // [0, 65536)
  const int cg = e >> 14, re = e & 16383;
  const int wv = re >> 12, li = re & 4095;
  const int rr = li >> 6;
  const int kq = ((li >> 3) & 7) ^ (rr & 7);
  const int j = li & 7;
  const int k = cg * 64 + kq * 8 + j;
  const int col = wv * 64 + rr;
  dst[z * 65536 + e] = bfb_(in[k * 256 + col]);
}

// ---------------- main kernel --------------------------------------------
#define PID_F1 0
#define PID_F2 1
#define PID_F4 2
#define PID_H1 3
#define PID_H2 4
#define PID_H4 5
#define PID_Q1 6
#define PID_Q3 7
#define PID_O1 8
#define PID_O3 9
#define PID_SR 10
#define PID_SK 11

// LDS offsets (u32 units)
#define OFF_WBUF  0       // [4 waves][2 bufs][2048 u32=8KB]
#define OFF_SREPT 16384   // [256][36] u32 rows (72 u16: 64 data + 8 pad)
#define OFF_SKEY  25600   // [64][132] u32 rows (264 u16: 256 data + 8 pad)
#define OFF_ATTW  34048   // [4 waves][64] f32
#define OFF_HF    34304   // [2][256] f32
#define OFF_XQR   34816   // 128 u32 (256 bf16)
#define OFF_XFH   34944
#define OFF_XO    35072
#define OFF_H2    35200   // [2][128]
#define OFF_Q2    35456   // [2][128]
#define LDS_U32   35712   // 142,848 B

#define BAR() asm volatile("s_waitcnt lgkmcnt(0)\n\ts_barrier" ::: "memory")
#define SB()  __builtin_amdgcn_sched_barrier(0)
#define VMW8() asm volatile("s_waitcnt vmcnt(8)" ::: "memory")

__device__ __forceinline__ float ulo(u32 x) { return __uint_as_float(x << 16); }
__device__ __forceinline__ float uhi(u32 x) { return __uint_as_float(x & 0xffff0000u); }
__device__ __forceinline__ u32 pk2(float a, float b) {
  return (u32)bfb_(a) | ((u32)bfb_(b) << 16);
}
__device__ __forceinline__ float sgm(float x) { return 1.f / (1.f + __expf(-x)); }
__device__ __forceinline__ float tnh(float x) { return 1.f - 2.f / (__expf(2.f * x) + 1.f); }

__global__ __launch_bounds__(256) void dagsage_main(
    const float* __restrict__ adj,
    const float* __restrict__ b_srep, const float* __restrict__ b_skey,
    const float* __restrict__ pf, const float* __restrict__ ph,
    const float* __restrict__ pq, const float* __restrict__ po,
    const u16* __restrict__ panels,
    float* __restrict__ outp) {
  __shared__ u32 lds[LDS_U32];
  const int t = threadIdx.x;
  const int w = t >> 6, l = t & 63;
  const int rr = l;                       // col-within-wave == lane
  const int b = blockIdx.x;

  // ---- init srepT / skey (out_nodes==0 -> rows are biases) ----
  {
    const float bs0 = b_srep[t];
    for (int j = 0; j < 32; ++j)
      lds[OFF_SREPT + t * 36 + j] = pk2(bs0, bs0);
    const int n = t >> 2, kk0 = (t & 3) * 32;
    for (int j = 0; j < 32; ++j) {
      const int kk = kk0 + j;
      lds[OFF_SKEY + n * 132 + (kk ^ ((n & 7) << 2))] =
          pk2(b_skey[2 * kk], b_skey[2 * kk + 1]);
    }
  }
  __syncthreads();

#define ISSUE(P, cg, pn) {                                                    \
    const u16* gs_ = panels + (((P) << 16) + ((cg) << 14) + (w << 12) + (l << 3)); \
    u32* lb_ = (u32*)(lds + OFF_WBUF + (w << 12) + ((pn) << 11));             \
    _Pragma("unroll")                                                         \
    for (int r_ = 0; r_ < 8; ++r_)                                            \
      __builtin_amdgcn_global_load_lds(                                       \
          (const __attribute__((address_space(1))) void*)(gs_ + (r_ << 9)),   \
          (__attribute__((address_space(3))) void*)(lb_ + (r_ << 8)),         \
          16, 0, 0);                                                          \
    SB(); }

#define COMPUTE(ACCV, XB, cg, pp) {                                           \
    const u32* wp_ = lds + OFF_WBUF + (w << 12) + ((pp) << 11);               \
    const u32* xp_ = lds + (XB) + ((cg) << 5);                                \
    _Pragma("unroll")                                                         \
    for (int kq_ = 0; kq_ < 8; ++kq_) {                                       \
      const u32x4 wv_ = *(const u32x4*)(wp_ + ((rr << 5) + ((kq_ << 2) ^ ((rr & 7) << 2)))); \
      const u32x4 xv_ = *(const u32x4*)(xp_ + (kq_ << 2));                    \
      _Pragma("unroll")                                                       \
      for (int m_ = 0; m_ < 4; ++m_) {                                        \
        ACCV = fmaf(ulo(xv_[m_]), ulo(wv_[m_]), ACCV);                        \
        ACCV = fmaf(uhi(xv_[m_]), uhi(wv_[m_]), ACCV);                        \
      } } }

#define SL(ACCV, XB, cg, PN, CGN)                                             \
    ISSUE(PN, CGN, ((cg) + 1) & 1); VMW8(); COMPUTE(ACCV, XB, cg, (cg) & 1); SB();

#define ITEM4(ACCV, XB, PS, PN)                                               \
    SL(ACCV, XB, 0, PS, 1) SL(ACCV, XB, 1, PS, 2)                             \
    SL(ACCV, XB, 2, PS, 3) SL(ACCV, XB, 3, PN, 0)

#define stb(off, v) (((u16*)(lds + (off)))[t] = bfb_(v))

#define QRES() {                                                              \
    float qr_ = 0.f;                                                          \
    const u32* sp_ = lds + OFF_SREPT + t * 36;                                \
    const float* ap_ = (const float*)(lds + OFF_ATTW) + (w << 6);             \
    _Pragma("unroll")                                                         \
    for (int nq_ = 0; nq_ < 8; ++nq_) {                                       \
      const u32x4 sv_ = *(const u32x4*)(sp_ + (nq_ << 2));                    \
      const f32x4 a0_ = *(const f32x4*)(ap_ + (nq_ << 3));                    \
      const f32x4 a1_ = *(const f32x4*)(ap_ + (nq_ << 3) + 4);                \
      qr_ = fmaf(a0_[0], ulo(sv_[0]), qr_); qr_ = fmaf(a0_[1], uhi(sv_[0]), qr_); \
      qr_ = fmaf(a0_[2], ulo(sv_[1]), qr_); qr_ = fmaf(a0_[3], uhi(sv_[1]), qr_); \
      qr_ = fmaf(a1_[0], ulo(sv_[2]), qr_); qr_ = fmaf(a1_[1], uhi(sv_[2]), qr_); \
      qr_ = fmaf(a1_[2], ulo(sv_[3]), qr_); qr_ = fmaf(a1_[3], uhi(sv_[3]), qr_); \
    }                                                                         \
    stb(OFF_XQR, qr_); }

#define LOGITS(CP) {                                                          \
    float la_ = 0.f;                                                          \
    const u32* kp_ = lds + OFF_SKEY + l * 132;                                \
    const u32* qp_ = lds + OFF_Q2 + (CP) * 128;                               \
    _Pragma("unroll")                                                         \
    for (int kq_ = 0; kq_ < 32; ++kq_) {                                      \
      const u32x4 kv_ = *(const u32x4*)(kp_ + ((kq_ << 2) ^ ((l & 7) << 2))); \
      const u32x4 qv_ = *(const u32x4*)(qp_ + (kq_ << 2));                    \
      _Pragma("unroll")                                                       \
      for (int m_ = 0; m_ < 4; ++m_) {                                        \
        la_ = fmaf(ulo(qv_[m_]), ulo(kv_[m_]), la_);                          \
        la_ = fmaf(uhi(qv_[m_]), uhi(kv_[m_]), la_);                          \
      } }                                                                     \
    float mx_ = la_;                                                          \
    _Pragma("unroll")                                                         \
    for (int o_ = 1; o_ < 64; o_ <<= 1) mx_ = fmaxf(mx_, __shfl_xor(mx_, o_, 64)); \
    const float e_ = __expf(la_ - mx_) * mk;                                  \
    float sm_ = e_;                                                           \
    _Pragma("unroll")                                                         \
    for (int o_ = 1; o_ < 64; o_ <<= 1) sm_ += __shfl_xor(sm_, o_, 64);       \
    ((float*)(lds + OFF_ATTW))[(w << 6) + l] = e_ / sm_; }

  // prologue: stage F1 chunk 0 into buffer 0
  ISSUE(PID_F1, 0, 0);

  const float bsv = b_srep[t];
  const float bkv = b_skey[t];

#pragma unroll 1
  for (int i = 0; i < 64; ++i) {
    const int ro = (b * 64 + i) * 256 + t;
    const float pfv = pf[ro], phv = ph[ro], pqv = pq[ro], pov = po[ro];
    const float mk = adj[(b * 64 + l) * 64 + i];

    // it0 attention weights (per-wave redundant): attw = mk / sum(mk)
    {
      float sm_ = mk;
#pragma unroll
      for (int o_ = 1; o_ < 64; o_ <<= 1) sm_ += __shfl_xor(sm_, o_, 64);
      ((float*)(lds + OFF_ATTW))[(w << 6) + l] = mk / sm_;
    }

    float Fa, Ha, Qa, frv, fhv, hv, qv;

    // ================= it0 =================
    QRES();
    BAR();
    Fa = 0.f; Ha = 0.f;
    ITEM4(Fa, OFF_XQR, PID_F1, PID_H1);
    ITEM4(Ha, OFF_XQR, PID_H1, PID_Q1);
    frv = sgm(Fa + pfv);
    hv = (1.f - frv) * tnh(Ha + phv);
    stb(OFF_H2, hv);
    ((float*)(lds + OFF_HF))[t] = hv;
    BAR();
    Qa = 0.f;
    ITEM4(Qa, OFF_H2, PID_Q1, PID_F1);
    qv = Qa + pqv;
    stb(OFF_Q2, qv);
    BAR();

// ================= iterations 1,2 =================
#define ITERB(CP, NP, XN)                                                     \
    LOGITS(CP);                                                               \
    QRES();                                                                   \
    BAR();                                                                    \
    Fa = 0.f; Ha = 0.f;                                                       \
    ITEM4(Fa, OFF_XQR, PID_F1, PID_F2);                                       \
    ITEM4(Fa, OFF_H2 + (CP) * 128, PID_F2, PID_F4);                           \
    ITEM4(Fa, OFF_Q2 + (CP) * 128, PID_F4, PID_H1);                           \
    ITEM4(Ha, OFF_XQR, PID_H1, PID_H4);                                       \
    ITEM4(Ha, OFF_Q2 + (CP) * 128, PID_H4, PID_H2);                           \
    frv = sgm(Fa + pfv);                                                      \
    fhv = frv * ((const float*)(lds + OFF_HF))[(CP) * 256 + t];               \
    stb(OFF_XFH, fhv);                                                        \
    BAR();                                                                    \
    Qa = 0.f;                                                                 \
    ITEM4(Ha, OFF_XFH, PID_H2, PID_Q3);                                       \
    ITEM4(Qa, OFF_Q2 + (CP) * 128, PID_Q3, PID_Q1);                           \
    hv = fhv + (1.f - frv) * tnh(Ha + phv);                                   \
    stb(OFF_H2 + (NP) * 128, hv);                                             \
    ((float*)(lds + OFF_HF))[(NP) * 256 + t] = hv;                            \
    BAR();                                                                    \
    ITEM4(Qa, OFF_H2 + (NP) * 128, PID_Q1, XN);                               \
    qv = Qa + pqv;                                                            \
    stb(OFF_Q2 + (NP) * 128, qv);                                             \
    BAR();

    ITERB(0, 1, PID_F1);
    ITERB(1, 0, PID_O1);

    // ================= P7: out_i =================
    {
      float Oa = 0.f;
      ITEM4(Oa, OFF_H2, PID_O1, PID_O3);
      ITEM4(Oa, OFF_Q2, PID_O3, PID_SR);
      const float ov = Oa + pov;
      outp[ro] = ov;
      stb(OFF_XO, ov);
      BAR();
    }
    // ================= P8: srep/skey row update =================
    {
      float Ra = 0.f, Ka = 0.f;
      ITEM4(Ra, OFF_XO, PID_SR, PID_SK);
      ITEM4(Ka, OFF_XO, PID_SK, PID_F1);   // stages next step's F1c0
      ((u16*)(lds + OFF_SREPT))[t * 72 + i] = bfb_(Ra + bsv);
      ((u16*)(lds + OFF_SKEY))[i * 264 + (t ^ ((i & 7) << 3))] = bfb_(Ka + bkv);
      BAR();
    }
  }
}

// ---------------------------------------------------------------------------
extern "C" void kernel_launch(void* const* d_in, const int* in_sizes, int n_in,
                              void* d_out, int out_size, void* d_ws, size_t ws_size,
                              hipStream_t stream) {
  const float* nodes    = (const float*)d_in[0];
  const float* adj      = (const float*)d_in[1];
  const float* W_self   = (const float*)d_in[2];
  const float* b_self   = (const float*)d_in[3];
  const float* W_srep   = (const float*)d_in[4];
  const float* b_srep   = (const float*)d_in[5];
  const float* W_skey   = (const float*)d_in[6];
  const float* b_skey   = (const float*)d_in[7];
  const float* W_forget = (const float*)d_in[8];
  const float* b_forget = (const float*)d_in[9];
  const float* W_hid    = (const float*)d_in[10];
  const float* b_hid    = (const float*)d_in[11];
  const float* W_query  = (const float*)d_in[12];
  const float* b_query  = (const float*)d_in[13];
  const float* W_out    = (const float*)d_in[14];
  const float* b_out    = (const float*)d_in[15];
  float* out = (float*)d_out;

  float* rep = (float*)d_ws;
  float* pf = rep + 524288;
  float* ph = pf + 524288;
  float* pq = ph + 524288;
  float* po = pq + 524288;
  u16* panels = (u16*)(po + 524288);

  hipMemcpyAsync(out + 524288, adj, 131072 * sizeof(float),
                 hipMemcpyDeviceToDevice, stream);

  C12 ca;
  ca.src[0]  = W_forget;             // F1  (rows 0:256   <- query_res)
  ca.src[1]  = W_forget + 256 * 256; // F2  (rows 256:512 <- hidden)
  ca.src[2]  = W_forget + 768 * 256; // F4  (rows 768:1024<- query)
  ca.src[3]  = W_hid;                // H1
  ca.src[4]  = W_hid + 256 * 256;    // H2  (<- forget*hidden)
  ca.src[5]  = W_hid + 768 * 256;    // H4
  ca.src[6]  = W_query;              // Q1  (rows 0:256 <- hidden)
  ca.src[7]  = W_query + 512 * 256;  // Q3  (rows 512:768 <- query)
  ca.src[8]  = W_out;                // O1
  ca.src[9]  = W_out + 512 * 256;    // O3
  ca.src[10] = W_srep;               // SR
  ca.src[11] = W_skey;               // SK
  cvt_panels<<<dim3(256, 12), 256, 0, stream>>>(ca, panels);

  G4 g1;
  for (int j = 0; j < 4; ++j) { g1.Bm[j] = W_self; g1.bias[j] = b_self; g1.C[j] = rep; }
  gemm16<<<dim3(128, 1), 256, 0, stream>>>(nodes, g1);

  G4 g2;
  g2.Bm[0] = W_forget + 512 * 256; g2.bias[0] = b_forget; g2.C[0] = pf;
  g2.Bm[1] = W_hid + 512 * 256;    g2.bias[1] = b_hid;    g2.C[1] = ph;
  g2.Bm[2] = W_query + 256 * 256;  g2.bias[2] = b_query;  g2.C[2] = pq;
  g2.Bm[3] = W_out + 256 * 256;    g2.bias[3] = b_out;    g2.C[3] = po;
  gemm16<<<dim3(128, 4), 256, 0, stream>>>(rep, g2);

  dagsage_main<<<32, 256, 0, stream>>>(adj, b_srep, b_skey,
                                       pf, ph, pq, po, panels, out);
}

// Round 11
// 5120.203 us; speedup vs baseline: 3.8086x; 3.8086x over previous
//
#include <hip/hip_runtime.h>
#include <hip/hip_bf16.h>

typedef unsigned int u32;
typedef unsigned char u8;
typedef unsigned short u16;
typedef u32 u32x4 __attribute__((ext_vector_type(4)));
typedef float f32x4 __attribute__((ext_vector_type(4)));

// ---------------------------------------------------------------------------
// B=32, N=64, R=256. 32 WGs x 256 threads, 1 batch/WG, thread t = col t.
// Weights stream global->LDS via global_load_lds (zero VGPR routing).
//
// ROUND-10 LESSON: the fully-unrolled step body (~100KB code) thrashed the
// 32KB I-cache every iteration at 1 wave/SIMD -> instruction-fetch bound
// (FETCH 1.1GB, VALUBusy 1.4%). This version drives the 23-item weight
// stream from descriptor tables through ONE chunk-loop instance (~5KB code,
// I-cache resident). Staging pipeline (vmcnt(8), dbuf) unchanged.
//
// Panel image per 32KB chunk (k-quarter cg): wave w's 8KB slice holds cols
// [64w,64w+64); col rr at rr*128B; 16B slot s holds k-group kq=s^(rr&7).
// ---------------------------------------------------------------------------

struct G4 { const float* Bm[4]; const float* bias[4]; float* C[4]; };

__global__ __launch_bounds__(256) void gemm16(const float* __restrict__ A, G4 g) {
  __shared__ float At[16 * 256];
  const int sub = blockIdx.y;
  const float* __restrict__ Bm = g.Bm[sub];
  const float* __restrict__ bias = g.bias[sub];
  float* __restrict__ C = g.C[sub];
  const int r0 = blockIdx.x * 16;
  const int t = threadIdx.x;
#pragma unroll
  for (int j = 0; j < 16; ++j) At[j * 256 + t] = A[(r0 + j) * 256 + t];
  __syncthreads();
  float acc[16];
#pragma unroll
  for (int j = 0; j < 16; ++j) acc[j] = 0.f;
  for (int k = 0; k < 256; ++k) {
    const float bv = Bm[k * 256 + t];
#pragma unroll
    for (int j = 0; j < 16; ++j) acc[j] = fmaf(At[j * 256 + k], bv, acc[j]);
  }
  const float bs = bias[t];
#pragma unroll
  for (int j = 0; j < 16; ++j) C[(r0 + j) * 256 + t] = acc[j] + bs;
}

struct C12 { const float* src[12]; };

__device__ __forceinline__ u16 bfb_(float x) {
  union { __hip_bfloat16 h; u16 u; } c; c.h = __float2bfloat16(x); return c.u;
}

__global__ __launch_bounds__(256) void cvt_panels(C12 c, u16* __restrict__ dst) {
  const int z = blockIdx.y;
  const float* __restrict__ in = c.src[z];
  const int e = blockIdx.x * 256 + threadIdx.x;   // [0, 65536)
  const int cg = e >> 14, re = e & 16383;
  const int wv = re >> 12, li = re & 4095;
  const int rr = li >> 6;
  const int kq = ((li >> 3) & 7) ^ (rr & 7);
  const int j = li & 7;
  const int k = cg * 64 + kq * 8 + j;
  const int col = wv * 64 + rr;
  dst[z * 65536 + e] = bfb_(in[k * 256 + col]);
}

// ---------------- main kernel --------------------------------------------
#define PID_F1 0
#define PID_F2 1
#define PID_F4 2
#define PID_H1 3
#define PID_H2 4
#define PID_H4 5
#define PID_Q1 6
#define PID_Q3 7
#define PID_O1 8
#define PID_O3 9
#define PID_SR 10
#define PID_SK 11

// LDS offsets (u32 units)
#define OFF_WBUF  0       // [4 waves][2 bufs][2048 u32 = 8KB]
#define OFF_SREPT 16384   // [256][36] u32 rows
#define OFF_SKEY  25600   // [64][132] u32 rows
#define OFF_ATTW  34048   // [4 waves][64] f32
#define OFF_HF    34304   // [2][256] f32
#define OFF_XQR   34816
#define OFF_XFH   34944
#define OFF_XO    35072
#define OFF_H2    35200   // [2][128]
#define OFF_Q2    35456   // [2][128]
#define LDS_U32   35712

#define BAR() asm volatile("s_waitcnt lgkmcnt(0)\n\ts_barrier" ::: "memory")
#define VMW8() asm volatile("s_waitcnt vmcnt(8)" ::: "memory")

__device__ __forceinline__ float ulo(u32 x) { return __uint_as_float(x << 16); }
__device__ __forceinline__ float uhi(u32 x) { return __uint_as_float(x & 0xffff0000u); }
__device__ __forceinline__ u32 pk2(float a, float b) {
  return (u32)bfb_(a) | ((u32)bfb_(b) << 16);
}
__device__ __forceinline__ float sgm(float x) { return 1.f / (1.f + __expf(-x)); }
__device__ __forceinline__ float tnh(float x) { return 1.f - 2.f / (__expf(2.f * x) + 1.f); }

// item pid for items 0..22 (+wrap F1): F1,H1,Q1 | F1,F2,F4,H1,H4,H2,Q3,Q1 |x2| O1,O3,SR,SK
__device__ const u8 IPID[24] = {0, 3, 6,
                                0, 1, 2, 3, 5, 4, 7, 6,
                                0, 1, 2, 3, 5, 4, 7, 6,
                                8, 9, 10, 11, 0};
// desc: tail(0..7) | p<<3 | att<<5 | asel<<6 | reset<<7 ; entry = xoff | desc<<16
#define DE(x, d) ((u32)(x) | ((u32)(d) << 16))
__device__ const u32 ITBL[23] = {
  DE(OFF_XQR,      0x80), DE(OFF_XQR,      0xC1), DE(OFF_H2,       0xA4),
  DE(OFF_XQR,      0x80), DE(OFF_H2,       0x00), DE(OFF_Q2,       0x00),
  DE(OFF_XQR,      0xC0), DE(OFF_Q2,       0x42), DE(OFF_XFH,      0x40),
  DE(OFF_Q2,       0x8B), DE(OFF_H2 + 128, 0x2C),
  DE(OFF_XQR,      0x80), DE(OFF_H2 + 128, 0x00), DE(OFF_Q2 + 128, 0x00),
  DE(OFF_XQR,      0xC0), DE(OFF_Q2 + 128, 0x4A), DE(OFF_XFH,      0x40),
  DE(OFF_Q2 + 128, 0x83), DE(OFF_H2,       0x04),
  DE(OFF_H2,       0x80), DE(OFF_Q2,       0x05),
  DE(OFF_XO,       0x86), DE(OFF_XO,       0x87)};

__device__ __forceinline__ void issue_chunk(const u16* __restrict__ panels,
                                            u32* lds, int w, int l,
                                            int pid, int cg, int buf) {
  const u16* gs = panels + ((pid << 16) + (cg << 14) + (w << 12) + (l << 3));
  u32* lb = lds + OFF_WBUF + (w << 12) + (buf << 11);
#pragma unroll
  for (int r = 0; r < 8; ++r)
    __builtin_amdgcn_global_load_lds(
        (const __attribute__((address_space(1))) void*)(gs + (r << 9)),
        (__attribute__((address_space(3))) void*)(lb + (r << 8)), 16, 0, 0);
}

__device__ __forceinline__ float compute_chunk(const u32* lds, int w, int rr,
                                               int xb, int cg, int pp) {
  const u32* wp = lds + OFF_WBUF + (w << 12) + (pp << 11) + (rr << 5);
  const u32* xp = lds + xb + (cg << 5);
  float acc = 0.f;
#pragma unroll
  for (int kq = 0; kq < 8; ++kq) {
    const u32x4 wv = *(const u32x4*)(wp + ((kq << 2) ^ ((rr & 7) << 2)));
    const u32x4 xv = *(const u32x4*)(xp + (kq << 2));
#pragma unroll
    for (int m = 0; m < 4; ++m) {
      acc = fmaf(ulo(xv[m]), ulo(wv[m]), acc);
      acc = fmaf(uhi(xv[m]), uhi(wv[m]), acc);
    }
  }
  return acc;
}

__device__ __forceinline__ void qres_phase(u32* lds, int w, int t) {
  float qr = 0.f;
  const u32* sp = lds + OFF_SREPT + t * 36;
  const float* ap = (const float*)(lds + OFF_ATTW) + (w << 6);
#pragma unroll
  for (int nq = 0; nq < 8; ++nq) {
    const u32x4 sv = *(const u32x4*)(sp + (nq << 2));
    const f32x4 a0 = *(const f32x4*)(ap + (nq << 3));
    const f32x4 a1 = *(const f32x4*)(ap + (nq << 3) + 4);
    qr = fmaf(a0[0], ulo(sv[0]), qr); qr = fmaf(a0[1], uhi(sv[0]), qr);
    qr = fmaf(a0[2], ulo(sv[1]), qr); qr = fmaf(a0[3], uhi(sv[1]), qr);
    qr = fmaf(a1[0], ulo(sv[2]), qr); qr = fmaf(a1[1], uhi(sv[2]), qr);
    qr = fmaf(a1[2], ulo(sv[3]), qr); qr = fmaf(a1[3], uhi(sv[3]), qr);
  }
  ((u16*)(lds + OFF_XQR))[t] = bfb_(qr);
}

__device__ __forceinline__ void logits_phase(u32* lds, int w, int l,
                                             float mk, int cp) {
  float la = 0.f;
  const u32* kp = lds + OFF_SKEY + l * 132;
  const u32* qp = lds + OFF_Q2 + cp * 128;
#pragma unroll
  for (int kq = 0; kq < 32; ++kq) {
    const u32x4 kv = *(const u32x4*)(kp + ((kq << 2) ^ ((l & 7) << 2)));
    const u32x4 qv = *(const u32x4*)(qp + (kq << 2));
#pragma unroll
    for (int m = 0; m < 4; ++m) {
      la = fmaf(ulo(qv[m]), ulo(kv[m]), la);
      la = fmaf(uhi(qv[m]), uhi(kv[m]), la);
    }
  }
  float mx = la;
#pragma unroll
  for (int o = 1; o < 64; o <<= 1) mx = fmaxf(mx, __shfl_xor(mx, o, 64));
  const float e = __expf(la - mx) * mk;
  float sm = e;
#pragma unroll
  for (int o = 1; o < 64; o <<= 1) sm += __shfl_xor(sm, o, 64);
  ((float*)(lds + OFF_ATTW))[(w << 6) + l] = e / sm;
}

__global__ __launch_bounds__(256) void dagsage_main(
    const float* __restrict__ adj,
    const float* __restrict__ b_srep, const float* __restrict__ b_skey,
    const float* __restrict__ pf, const float* __restrict__ ph,
    const float* __restrict__ pq, const float* __restrict__ po,
    const u16* __restrict__ panels,
    float* __restrict__ outp) {
  __shared__ u32 lds[LDS_U32];
  const int t = threadIdx.x;
  const int w = t >> 6, l = t & 63;
  const int b = blockIdx.x;

  // ---- init srepT / skey (out_nodes==0 -> rows are biases) ----
  {
    const float bs0 = b_srep[t];
    for (int j = 0; j < 32; ++j)
      lds[OFF_SREPT + t * 36 + j] = pk2(bs0, bs0);
    const int n = t >> 2, kk0 = (t & 3) * 32;
    for (int j = 0; j < 32; ++j) {
      const int kk = kk0 + j;
      lds[OFF_SKEY + n * 132 + (kk ^ ((n & 7) << 2))] =
          pk2(b_skey[2 * kk], b_skey[2 * kk + 1]);
    }
  }
  __syncthreads();

  const float bsv = b_srep[t];
  const float bkv = b_skey[t];

  issue_chunk(panels, lds, w, l, PID_F1, 0, 0);   // prologue stage F1c0 -> buf0

#pragma unroll 1
  for (int i = 0; i < 64; ++i) {
    const int ro = (b * 64 + i) * 256 + t;
    const float pfv = pf[ro], phv = ph[ro], pqv = pq[ro], pov = po[ro];
    const float mk = adj[(b * 64 + l) * 64 + i];

    // it0 attention weights (per-wave redundant): attw = mk / sum(mk)
    {
      float sm = mk;
#pragma unroll
      for (int o = 1; o < 64; o <<= 1) sm += __shfl_xor(sm, o, 64);
      ((float*)(lds + OFF_ATTW))[(w << 6) + l] = mk / sm;
    }
    qres_phase(lds, w, t);
    BAR();

    float a0 = 0.f, a1 = 0.f, frv = 0.f, fhv = 0.f;
    u32 cur = 0;

#pragma unroll 1
    for (int n = 0; n < 92; ++n) {
      const int cg = n & 3;
      if (cg == 0) {
        cur = ITBL[n >> 2];
        const u32 d = cur >> 16;
        if (d & 0x80) { if (d & 0x40) a1 = 0.f; else a0 = 0.f; }
      }
      const int pidn = IPID[(n + 1) >> 2];
      issue_chunk(panels, lds, w, l, pidn, (n + 1) & 3, (n + 1) & 1);
      VMW8();
      const float tacc = compute_chunk(lds, w, l, (int)(cur & 0xFFFF), cg, n & 1);
      const u32 d = cur >> 16;
      if (d & 0x40) a1 += tacc; else a0 += tacc;

      if (cg == 3) {
        const int p = (d >> 3) & 1;
        switch (d & 7) {
          case 1: {  // FH0
            frv = sgm(a0 + pfv);
            const float hv = (1.f - frv) * tnh(a1 + phv);
            ((u16*)(lds + OFF_H2))[t] = bfb_(hv);
            ((float*)(lds + OFF_HF))[t] = hv;
            BAR();
          } break;
          case 2: {  // F
            frv = sgm(a0 + pfv);
            fhv = frv * ((const float*)(lds + OFF_HF))[p * 256 + t];
            ((u16*)(lds + OFF_XFH))[t] = bfb_(fhv);
            BAR();
          } break;
          case 3: {  // H
            const float hv = fhv + (1.f - frv) * tnh(a1 + phv);
            ((u16*)(lds + OFF_H2 + p * 128))[t] = bfb_(hv);
            ((float*)(lds + OFF_HF))[p * 256 + t] = hv;
            BAR();
          } break;
          case 4: {  // Q (+optional attention for next iter)
            const float qv = a0 + pqv;
            ((u16*)(lds + OFF_Q2 + p * 128))[t] = bfb_(qv);
            BAR();
            if (d & 0x20) {
              logits_phase(lds, w, l, mk, p);
              qres_phase(lds, w, t);
              BAR();
            }
          } break;
          case 5: {  // O
            const float ov = a0 + pov;
            outp[ro] = ov;
            ((u16*)(lds + OFF_XO))[t] = bfb_(ov);
            BAR();
          } break;
          case 6: {  // R: srep row i update
            ((u16*)(lds + OFF_SREPT))[t * 72 + i] = bfb_(a0 + bsv);
          } break;
          case 7: {  // K: skey row i update
            ((u16*)(lds + OFF_SKEY))[i * 264 + (t ^ ((i & 7) << 3))] =
                bfb_(a0 + bkv);
            BAR();
          } break;
          default: break;
        }
      }
    }
  }
}

// ---------------------------------------------------------------------------
extern "C" void kernel_launch(void* const* d_in, const int* in_sizes, int n_in,
                              void* d_out, int out_size, void* d_ws, size_t ws_size,
                              hipStream_t stream) {
  const float* nodes    = (const float*)d_in[0];
  const float* adj      = (const float*)d_in[1];
  const float* W_self   = (const float*)d_in[2];
  const float* b_self   = (const float*)d_in[3];
  const float* W_srep   = (const float*)d_in[4];
  const float* b_srep   = (const float*)d_in[5];
  const float* W_skey   = (const float*)d_in[6];
  const float* b_skey   = (const float*)d_in[7];
  const float* W_forget = (const float*)d_in[8];
  const float* b_forget = (const float*)d_in[9];
  const float* W_hid    = (const float*)d_in[10];
  const float* b_hid    = (const float*)d_in[11];
  const float* W_query  = (const float*)d_in[12];
  const float* b_query  = (const float*)d_in[13];
  const float* W_out    = (const float*)d_in[14];
  const float* b_out    = (const float*)d_in[15];
  float* out = (float*)d_out;

  float* rep = (float*)d_ws;
  float* pf = rep + 524288;
  float* ph = pf + 524288;
  float* pq = ph + 524288;
  float* po = pq + 524288;
  u16* panels = (u16*)(po + 524288);

  hipMemcpyAsync(out + 524288, adj, 131072 * sizeof(float),
                 hipMemcpyDeviceToDevice, stream);

  C12 ca;
  ca.src[0]  = W_forget;             // F1  (rows 0:256   <- query_res)
  ca.src[1]  = W_forget + 256 * 256; // F2  (rows 256:512 <- hidden)
  ca.src[2]  = W_forget + 768 * 256; // F4  (rows 768:1024<- query)
  ca.src[3]  = W_hid;                // H1
  ca.src[4]  = W_hid + 256 * 256;    // H2  (<- forget*hidden)
  ca.src[5]  = W_hid + 768 * 256;    // H4
  ca.src[6]  = W_query;              // Q1  (rows 0:256 <- hidden)
  ca.src[7]  = W_query + 512 * 256;  // Q3  (rows 512:768 <- query)
  ca.src[8]  = W_out;                // O1
  ca.src[9]  = W_out + 512 * 256;    // O3
  ca.src[10] = W_srep;               // SR
  ca.src[11] = W_skey;               // SK
  cvt_panels<<<dim3(256, 12), 256, 0, stream>>>(ca, panels);

  G4 g1;
  for (int j = 0; j < 4; ++j) { g1.Bm[j] = W_self; g1.bias[j] = b_self; g1.C[j] = rep; }
  gemm16<<<dim3(128, 1), 256, 0, stream>>>(nodes, g1);

  G4 g2;
  g2.Bm[0] = W_forget + 512 * 256; g2.bias[0] = b_forget; g2.C[0] = pf;
  g2.Bm[1] = W_hid + 512 * 256;    g2.bias[1] = b_hid;    g2.C[1] = ph;
  g2.Bm[2] = W_query + 256 * 256;  g2.bias[2] = b_query;  g2.C[2] = pq;
  g2.Bm[3] = W_out + 256 * 256;    g2.bias[3] = b_out;    g2.C[3] = po;
  gemm16<<<dim3(128, 4), 256, 0, stream>>>(rep, g2);

  dagsage_main<<<32, 256, 0, stream>>>(adj, b_srep, b_skey,
                                       pf, ph, pq, po, panels, out);
}

// Round 12
// 3023.783 us; speedup vs baseline: 6.4492x; 1.6933x over previous
//
#include <hip/hip_runtime.h>
#include <hip/hip_bf16.h>

typedef unsigned int u32;
typedef unsigned short u16;
typedef u32 u32x4 __attribute__((ext_vector_type(4)));
typedef float f32x4 __attribute__((ext_vector_type(4)));

// ---------------------------------------------------------------------------
// B=32, N=64, R=256. 32 WGs x 256 threads, 1 batch/WG, thread t = col t.
//
// ROUND-11 LESSON: LDS-staged weights were latency-chain bound (~2070 cyc per
// 8KB chunk; implied global_load_lds completion ~3500 cyc; nothing else
// saturated). Latency x BW product exceeds LDS, so deeper LDS pipelining
// can't cover it. THIS ROUND: weights stream global->VGPR (2x32-VGPR double
// buffer, plain dwordx4 loads, L2 latency ~200-400) inside the round-11
// descriptor-driven compact loop (~5KB code, I-cache safe; demand ~110 <128
// so no spill, unlike round 9's ~150). x-buffers now f32 (halves unpack
// VALU, broadcast LDS reads, better accuracy). Weight LDS traffic gone.
//
// Panel layout (u16 e in panel): e = cg*16384 + w*4096 + r*512 + l*8 + j
//   -> k = cg*64 + r*8 + j, col = w*64 + l.  Lane l of wave w reads 16B at
//   contiguous 1KB-per-instruction addresses (perfect coalescing).
// ---------------------------------------------------------------------------

struct G4 { const float* Bm[4]; const float* bias[4]; float* C[4]; };

__global__ __launch_bounds__(256) void gemm16(const float* __restrict__ A, G4 g) {
  __shared__ float At[16 * 256];
  const int sub = blockIdx.y;
  const float* __restrict__ Bm = g.Bm[sub];
  const float* __restrict__ bias = g.bias[sub];
  float* __restrict__ C = g.C[sub];
  const int r0 = blockIdx.x * 16;
  const int t = threadIdx.x;
#pragma unroll
  for (int j = 0; j < 16; ++j) At[j * 256 + t] = A[(r0 + j) * 256 + t];
  __syncthreads();
  float acc[16];
#pragma unroll
  for (int j = 0; j < 16; ++j) acc[j] = 0.f;
  for (int k = 0; k < 256; ++k) {
    const float bv = Bm[k * 256 + t];
#pragma unroll
    for (int j = 0; j < 16; ++j) acc[j] = fmaf(At[j * 256 + k], bv, acc[j]);
  }
  const float bs = bias[t];
#pragma unroll
  for (int j = 0; j < 16; ++j) C[(r0 + j) * 256 + t] = acc[j] + bs;
}

struct C12 { const float* src[12]; };

__device__ __forceinline__ u16 bfb_(float x) {
  union { __hip_bfloat16 h; u16 u; } c; c.h = __float2bfloat16(x); return c.u;
}

__global__ __launch_bounds__(256) void cvt_panels(C12 c, u16* __restrict__ dst) {
  const int z = blockIdx.y;
  const float* __restrict__ in = c.src[z];
  const int e = blockIdx.x * 256 + threadIdx.x;   // [0, 65536)
  const int cg = e >> 14, w = (e >> 12) & 3, r = (e >> 9) & 7;
  const int l = (e >> 3) & 63, j = e & 7;
  const int k = cg * 64 + r * 8 + j;
  const int col = w * 64 + l;
  dst[z * 65536 + e] = bfb_(in[k * 256 + col]);
}

// ---------------- main kernel --------------------------------------------
#define PID_F1 0

// LDS offsets (u32 units)
#define OFF_SREPT 0       // [256 cols][36] u32 rows (64 nodes bf16 + pad)
#define OFF_SKEY  9216    // [64 nodes][132] u32 rows (256 k bf16, XOR-swz)
#define OFF_ATTW  17664   // [4 waves][64] f32
#define OFF_XQR   17920   // [256] f32
#define OFF_XFH   18176   // [256] f32
#define OFF_XO    18432   // [256] f32
#define OFF_H2    18688   // [2][256] f32
#define OFF_Q2    19200   // [2][256] f32
#define LDS_U32   19712   // 78,848 B

#define BAR() asm volatile("s_waitcnt lgkmcnt(0)\n\ts_barrier" ::: "memory")
#define SB()  __builtin_amdgcn_sched_barrier(0)

__device__ __forceinline__ float ulo(u32 x) { return __uint_as_float(x << 16); }
__device__ __forceinline__ float uhi(u32 x) { return __uint_as_float(x & 0xffff0000u); }
__device__ __forceinline__ u32 pk2(float a, float b) {
  return (u32)bfb_(a) | ((u32)bfb_(b) << 16);
}
__device__ __forceinline__ float sgm(float x) { return 1.f / (1.f + __expf(-x)); }
__device__ __forceinline__ float tnh(float x) { return 1.f - 2.f / (__expf(2.f * x) + 1.f); }

// item pids: F1,H1,Q1 | F1,F2,F4,H1,H4,H2,Q3,Q1 | x2 | O1,O3,SR,SK | F1(wrap)
// packed 4-bit nibbles, idx 0..23
__device__ __forceinline__ int pid_of(int idx) {
  const unsigned long long P0 = 0x5321067453210630ull;   // idx 0..15
  const unsigned long long P1 = 0x000000000BA98674ull;   // idx 16..23
  const unsigned long long v = (idx < 16) ? (P0 >> (idx * 4))
                                          : (P1 >> ((idx - 16) * 4));
  return (int)(v & 15);
}

// desc: tail(0..7) | p<<3 | att<<5 | asel<<6 | reset<<7 ; entry = xoff|desc<<16
#define DE(x, d) ((u32)(x) | ((u32)(d) << 16))
__device__ const u32 ITBL[23] = {
  DE(OFF_XQR,       0x80), DE(OFF_XQR,       0xC1), DE(OFF_H2,        0xA4),
  DE(OFF_XQR,       0x80), DE(OFF_H2,        0x00), DE(OFF_Q2,        0x00),
  DE(OFF_XQR,       0xC0), DE(OFF_Q2,        0x42), DE(OFF_XFH,       0x40),
  DE(OFF_Q2,        0x8B), DE(OFF_H2 + 256,  0x2C),
  DE(OFF_XQR,       0x80), DE(OFF_H2 + 256,  0x00), DE(OFF_Q2 + 256,  0x00),
  DE(OFF_XQR,       0xC0), DE(OFF_Q2 + 256,  0x4A), DE(OFF_XFH,       0x40),
  DE(OFF_Q2 + 256,  0x83), DE(OFF_H2,        0x04),
  DE(OFF_H2,        0x80), DE(OFF_Q2,        0x05),
  DE(OFF_XO,        0x86), DE(OFF_XO,        0x87)};

// load one K-quarter slice (32 VGPRs) for this lane's col
#define ISSQ(BUF, P, CG) {                                                    \
    const u32* gp_ = pan_lane + (((P) << 15) + ((CG) << 13));                 \
    _Pragma("unroll")                                                         \
    for (int r_ = 0; r_ < 8; ++r_) BUF[r_] = *(const u32x4*)(gp_ + (r_ << 8)); \
    SB(); }

__device__ __forceinline__ float cq(const u32x4 (&buf)[8], const float* xp) {
  float a = 0.f;
#pragma unroll
  for (int r = 0; r < 8; ++r) {
    const u32x4 wv = buf[r];
    const f32x4 x0 = *(const f32x4*)(xp + r * 8);
    const f32x4 x1 = *(const f32x4*)(xp + r * 8 + 4);
    a = fmaf(ulo(wv[0]), x0[0], a); a = fmaf(uhi(wv[0]), x0[1], a);
    a = fmaf(ulo(wv[1]), x0[2], a); a = fmaf(uhi(wv[1]), x0[3], a);
    a = fmaf(ulo(wv[2]), x1[0], a); a = fmaf(uhi(wv[2]), x1[1], a);
    a = fmaf(ulo(wv[3]), x1[2], a); a = fmaf(uhi(wv[3]), x1[3], a);
  }
  return a;
}

__device__ __forceinline__ void qres_phase(u32* lds, int w, int t) {
  float qr = 0.f;
  const u32* sp = lds + OFF_SREPT + t * 36;
  const float* ap = (const float*)(lds + OFF_ATTW) + (w << 6);
#pragma unroll
  for (int nq = 0; nq < 8; ++nq) {
    const u32x4 sv = *(const u32x4*)(sp + (nq << 2));
    const f32x4 a0 = *(const f32x4*)(ap + (nq << 3));
    const f32x4 a1 = *(const f32x4*)(ap + (nq << 3) + 4);
    qr = fmaf(a0[0], ulo(sv[0]), qr); qr = fmaf(a0[1], uhi(sv[0]), qr);
    qr = fmaf(a0[2], ulo(sv[1]), qr); qr = fmaf(a0[3], uhi(sv[1]), qr);
    qr = fmaf(a1[0], ulo(sv[2]), qr); qr = fmaf(a1[1], uhi(sv[2]), qr);
    qr = fmaf(a1[2], ulo(sv[3]), qr); qr = fmaf(a1[3], uhi(sv[3]), qr);
  }
  ((float*)(lds + OFF_XQR))[t] = qr;
}

__device__ __forceinline__ void logits_phase(u32* lds, int w, int l,
                                             float mk, int cp) {
  float la = 0.f;
  const u32* kp = lds + OFF_SKEY + l * 132;
  const float* qp = (const float*)(lds + OFF_Q2 + cp * 256);
#pragma unroll
  for (int kq = 0; kq < 32; ++kq) {
    const u32x4 kv = *(const u32x4*)(kp + ((kq << 2) ^ ((l & 7) << 2)));
    const f32x4 q0 = *(const f32x4*)(qp + (kq << 3));
    const f32x4 q1 = *(const f32x4*)(qp + (kq << 3) + 4);
    la = fmaf(ulo(kv[0]), q0[0], la); la = fmaf(uhi(kv[0]), q0[1], la);
    la = fmaf(ulo(kv[1]), q0[2], la); la = fmaf(uhi(kv[1]), q0[3], la);
    la = fmaf(ulo(kv[2]), q1[0], la); la = fmaf(uhi(kv[2]), q1[1], la);
    la = fmaf(ulo(kv[3]), q1[2], la); la = fmaf(uhi(kv[3]), q1[3], la);
  }
  float mx = la;
#pragma unroll
  for (int o = 1; o < 64; o <<= 1) mx = fmaxf(mx, __shfl_xor(mx, o, 64));
  const float e = __expf(la - mx) * mk;
  float sm = e;
#pragma unroll
  for (int o = 1; o < 64; o <<= 1) sm += __shfl_xor(sm, o, 64);
  ((float*)(lds + OFF_ATTW))[(w << 6) + l] = e / sm;
}

__global__ __launch_bounds__(256) void dagsage_main(
    const float* __restrict__ adj,
    const float* __restrict__ b_srep, const float* __restrict__ b_skey,
    const float* __restrict__ pf, const float* __restrict__ ph,
    const float* __restrict__ pq, const float* __restrict__ po,
    const u16* __restrict__ panels,
    float* __restrict__ outp) {
  __shared__ u32 lds[LDS_U32];
  const int t = threadIdx.x;
  const int w = t >> 6, l = t & 63;
  const int b = blockIdx.x;

  // ---- init srepT / skey (out_nodes==0 -> rows are biases) ----
  {
    const float bs0 = b_srep[t];
    for (int j = 0; j < 32; ++j)
      lds[OFF_SREPT + t * 36 + j] = pk2(bs0, bs0);
    const int n = t >> 2, kk0 = (t & 3) * 32;
    for (int j = 0; j < 32; ++j) {
      const int kk = kk0 + j;
      lds[OFF_SKEY + n * 132 + (kk ^ ((n & 7) << 2))] =
          pk2(b_skey[2 * kk], b_skey[2 * kk + 1]);
    }
  }
  __syncthreads();

  const float bsv = b_srep[t];
  const float bkv = b_skey[t];
  const u32* pan_lane = (const u32*)panels + (w << 11) + (l << 2);

  u32x4 bufA[8], bufB[8];
  ISSQ(bufA, PID_F1, 0);   // prologue: F1 quarter 0

#pragma unroll 1
  for (int i = 0; i < 64; ++i) {
    const int ro = (b * 64 + i) * 256 + t;
    const float pfv = pf[ro], phv = ph[ro], pqv = pq[ro], pov = po[ro];
    const float mk = adj[(b * 64 + l) * 64 + i];

    // it0 attention weights (per-wave copy): attw = mk / sum(mk)
    {
      float sm = mk;
#pragma unroll
      for (int o = 1; o < 64; o <<= 1) sm += __shfl_xor(sm, o, 64);
      ((float*)(lds + OFF_ATTW))[(w << 6) + l] = mk / sm;
    }
    qres_phase(lds, w, t);
    BAR();

    float a0 = 0.f, a1 = 0.f, frv = 0.f, fhv = 0.f;

#pragma unroll 1
    for (int it = 0; it < 23; ++it) {
      const u32 cur = ITBL[it];
      const u32 d = cur >> 16;
      const float* xp = (const float*)(lds + (cur & 0xFFFF));
      const int pc = pid_of(it);
      const int pn = pid_of(it + 1);

      float acc;
      ISSQ(bufB, pc, 1); acc  = cq(bufA, xp);       SB();
      ISSQ(bufA, pc, 2); acc += cq(bufB, xp + 64);  SB();
      ISSQ(bufB, pc, 3); acc += cq(bufA, xp + 128); SB();
      ISSQ(bufA, pn, 0); acc += cq(bufB, xp + 192); SB();

      if (d & 0x80) { if (d & 0x40) a1 = acc;  else a0 = acc; }
      else          { if (d & 0x40) a1 += acc; else a0 += acc; }

      const int p = (d >> 3) & 1;
      switch (d & 7) {
        case 1: {  // FH0
          frv = sgm(a0 + pfv);
          const float hv = (1.f - frv) * tnh(a1 + phv);
          ((float*)(lds + OFF_H2))[t] = hv;
          BAR();
        } break;
        case 2: {  // F
          frv = sgm(a0 + pfv);
          fhv = frv * ((const float*)(lds + OFF_H2))[p * 256 + t];
          ((float*)(lds + OFF_XFH))[t] = fhv;
          BAR();
        } break;
        case 3: {  // H
          const float hv = fhv + (1.f - frv) * tnh(a1 + phv);
          ((float*)(lds + OFF_H2))[p * 256 + t] = hv;
          BAR();
        } break;
        case 4: {  // Q (+optional attention for next iteration)
          ((float*)(lds + OFF_Q2))[p * 256 + t] = a0 + pqv;
          BAR();
          if (d & 0x20) {
            logits_phase(lds, w, l, mk, p);
            qres_phase(lds, w, t);
            BAR();
          }
        } break;
        case 5: {  // O
          const float ov = a0 + pov;
          outp[ro] = ov;
          ((float*)(lds + OFF_XO))[t] = ov;
          BAR();
        } break;
        case 6: {  // SR: srep row i update (own col -> no barrier needed)
          ((u16*)(lds + OFF_SREPT))[t * 72 + i] = bfb_(a0 + bsv);
        } break;
        case 7: {  // SK: skey row i update
          ((u16*)(lds + OFF_SKEY))[i * 264 + (t ^ ((i & 7) << 3))] =
              bfb_(a0 + bkv);
          BAR();
        } break;
        default: break;
      }
    }
  }
}

// ---------------------------------------------------------------------------
extern "C" void kernel_launch(void* const* d_in, const int* in_sizes, int n_in,
                              void* d_out, int out_size, void* d_ws, size_t ws_size,
                              hipStream_t stream) {
  const float* nodes    = (const float*)d_in[0];
  const float* adj      = (const float*)d_in[1];
  const float* W_self   = (const float*)d_in[2];
  const float* b_self   = (const float*)d_in[3];
  const float* W_srep   = (const float*)d_in[4];
  const float* b_srep   = (const float*)d_in[5];
  const float* W_skey   = (const float*)d_in[6];
  const float* b_skey   = (const float*)d_in[7];
  const float* W_forget = (const float*)d_in[8];
  const float* b_forget = (const float*)d_in[9];
  const float* W_hid    = (const float*)d_in[10];
  const float* b_hid    = (const float*)d_in[11];
  const float* W_query  = (const float*)d_in[12];
  const float* b_query  = (const float*)d_in[13];
  const float* W_out    = (const float*)d_in[14];
  const float* b_out    = (const float*)d_in[15];
  float* out = (float*)d_out;

  float* rep = (float*)d_ws;
  float* pf = rep + 524288;
  float* ph = pf + 524288;
  float* pq = ph + 524288;
  float* po = pq + 524288;
  u16* panels = (u16*)(po + 524288);

  hipMemcpyAsync(out + 524288, adj, 131072 * sizeof(float),
                 hipMemcpyDeviceToDevice, stream);

  C12 ca;
  ca.src[0]  = W_forget;             // F1  (rows 0:256   <- query_res)
  ca.src[1]  = W_forget + 256 * 256; // F2  (rows 256:512 <- hidden)
  ca.src[2]  = W_forget + 768 * 256; // F4  (rows 768:1024<- query)
  ca.src[3]  = W_hid;                // H1
  ca.src[4]  = W_hid + 256 * 256;    // H2  (<- forget*hidden)
  ca.src[5]  = W_hid + 768 * 256;    // H4
  ca.src[6]  = W_query;              // Q1  (rows 0:256 <- hidden)
  ca.src[7]  = W_query + 512 * 256;  // Q3  (rows 512:768 <- query)
  ca.src[8]  = W_out;                // O1
  ca.src[9]  = W_out + 512 * 256;    // O3
  ca.src[10] = W_srep;               // SR
  ca.src[11] = W_skey;               // SK
  cvt_panels<<<dim3(256, 12), 256, 0, stream>>>(ca, panels);

  G4 g1;
  for (int j = 0; j < 4; ++j) { g1.Bm[j] = W_self; g1.bias[j] = b_self; g1.C[j] = rep; }
  gemm16<<<dim3(128, 1), 256, 0, stream>>>(nodes, g1);

  G4 g2;
  g2.Bm[0] = W_forget + 512 * 256; g2.bias[0] = b_forget; g2.C[0] = pf;
  g2.Bm[1] = W_hid + 512 * 256;    g2.bias[1] = b_hid;    g2.C[1] = ph;
  g2.Bm[2] = W_query + 256 * 256;  g2.bias[2] = b_query;  g2.C[2] = pq;
  g2.Bm[3] = W_out + 256 * 256;    g2.bias[3] = b_out;    g2.C[3] = po;
  gemm16<<<dim3(128, 4), 256, 0, stream>>>(rep, g2);

  dagsage_main<<<32, 256, 0, stream>>>(adj, b_srep, b_skey,
                                       pf, ph, pq, po, panels, out);
}

// Round 13
// 2722.047 us; speedup vs baseline: 7.1641x; 1.1108x over previous
//
#include <hip/hip_runtime.h>
#include <hip/hip_bf16.h>

typedef unsigned int u32;
typedef unsigned short u16;
typedef u32 u32x4 __attribute__((ext_vector_type(4)));
typedef float f32x4 __attribute__((ext_vector_type(4)));

// ---------------------------------------------------------------------------
// B=32, N=64, R=256. 32 WGs x 512 threads, 1 batch/WG.
// Thread (g=t>>8, col=t&255) computes K-half [128g,128g+128) of column col.
//
// ROUND-12 LESSON: compact descriptor loop + VGPR weight dbuf = 3.02ms, no
// spill, but 1 wave/SIMD -> every L2 latency a hard stall (VALUBusy ~50% on
// active CUs). THIS ROUND: (1) 512-thr K-split -> 2 waves/SIMD TLP; item
// tails reduce the two K-half partials via LDS scratch (REDA/REDB) with a
// reduce-barrier, g0 computes the nonlinearity. (2) f16 weights/state: the
// (float)_Float16 * f32 fma pattern folds to v_fma_mix_f32 (no unpack ops);
// no regression if unfused. Panels stay 1.5MB (L2-resident per XCD).
//
// Panel u16 layout unchanged: e = cg*16384 + w4*4096 + r*512 + l*8 + j
//   -> k = cg*64+r*8+j, col = w4*64+l; 1KB contiguous per wave instruction.
// ---------------------------------------------------------------------------

struct G4 { const float* Bm[4]; const float* bias[4]; float* C[4]; };

__global__ __launch_bounds__(256) void gemm16(const float* __restrict__ A, G4 g) {
  __shared__ float At[16 * 256];
  const int sub = blockIdx.y;
  const float* __restrict__ Bm = g.Bm[sub];
  const float* __restrict__ bias = g.bias[sub];
  float* __restrict__ C = g.C[sub];
  const int r0 = blockIdx.x * 16;
  const int t = threadIdx.x;
#pragma unroll
  for (int j = 0; j < 16; ++j) At[j * 256 + t] = A[(r0 + j) * 256 + t];
  __syncthreads();
  float acc[16];
#pragma unroll
  for (int j = 0; j < 16; ++j) acc[j] = 0.f;
  for (int k = 0; k < 256; ++k) {
    const float bv = Bm[k * 256 + t];
#pragma unroll
    for (int j = 0; j < 16; ++j) acc[j] = fmaf(At[j * 256 + k], bv, acc[j]);
  }
  const float bs = bias[t];
#pragma unroll
  for (int j = 0; j < 16; ++j) C[(r0 + j) * 256 + t] = acc[j] + bs;
}

struct C12 { const float* src[12]; };

__device__ __forceinline__ u16 f16b(float x) {
  union { _Float16 h; u16 u; } c; c.h = (_Float16)x; return c.u;
}
__device__ __forceinline__ u32 pk2f(float a, float b) {
  return (u32)f16b(a) | ((u32)f16b(b) << 16);
}
__device__ __forceinline__ float flo(u32 x) {
  union { u32 u; _Float16 h[2]; } c; c.u = x; return (float)c.h[0];
}
__device__ __forceinline__ float fhi(u32 x) {
  union { u32 u; _Float16 h[2]; } c; c.u = x; return (float)c.h[1];
}

__global__ __launch_bounds__(256) void cvt_panels(C12 c, u16* __restrict__ dst) {
  const int z = blockIdx.y;
  const float* __restrict__ in = c.src[z];
  const int e = blockIdx.x * 256 + threadIdx.x;   // [0, 65536)
  const int cg = e >> 14, w = (e >> 12) & 3, r = (e >> 9) & 7;
  const int l = (e >> 3) & 63, j = e & 7;
  const int k = cg * 64 + r * 8 + j;
  const int col = w * 64 + l;
  dst[z * 65536 + e] = f16b(in[k * 256 + col]);
}

// ---------------- main kernel --------------------------------------------
#define PID_F1 0

// LDS offsets (u32 units)
#define OFF_SREPT 0       // [256 cols][36] u32 rows (64 nodes f16 + pad)
#define OFF_SKEY  9216    // [64 nodes][132] u32 rows (256 k f16, XOR-swz)
#define OFF_ATTW  17664   // [8 waves][64] f32
#define OFF_XQR   18176   // [256] f32
#define OFF_XFH   18432   // [256] f32
#define OFF_XO    18688   // [256] f32
#define OFF_H2    18944   // [2][256] f32
#define OFF_Q2    19456   // [2][256] f32
#define OFF_REDA  19968   // [256] f32 cross-half partial a0
#define OFF_REDB  20224   // [256] f32 cross-half partial a1 (and tail-6 a0)
#define LDS_U32   20480   // 81,920 B -> 1 WG/CU, 8 waves, 2/SIMD

#define BAR() asm volatile("s_waitcnt lgkmcnt(0)\n\ts_barrier" ::: "memory")
#define SB()  __builtin_amdgcn_sched_barrier(0)

__device__ __forceinline__ float sgm(float x) { return 1.f / (1.f + __expf(-x)); }
__device__ __forceinline__ float tnh(float x) { return 1.f - 2.f / (__expf(2.f * x) + 1.f); }

// item pids: F1,H1,Q1 | F1,F2,F4,H1,H4,H2,Q3,Q1 | x2 | O1,O3,SR,SK | F1(wrap)
__device__ __forceinline__ int pid_of(int idx) {
  const unsigned long long P0 = 0x5321067453210630ull;   // idx 0..15
  const unsigned long long P1 = 0x000000000BA98674ull;   // idx 16..23
  const unsigned long long v = (idx < 16) ? (P0 >> (idx * 4))
                                          : (P1 >> ((idx - 16) * 4));
  return (int)(v & 15);
}

// desc: tail(0..7) | p<<3 | att<<5 | asel<<6 | reset<<7 ; entry = xoff|desc<<16
#define DE(x, d) ((u32)(x) | ((u32)(d) << 16))
__device__ const u32 ITBL[23] = {
  DE(OFF_XQR,       0x80), DE(OFF_XQR,       0xC1), DE(OFF_H2,        0xA4),
  DE(OFF_XQR,       0x80), DE(OFF_H2,        0x00), DE(OFF_Q2,        0x00),
  DE(OFF_XQR,       0xC0), DE(OFF_Q2,        0x42), DE(OFF_XFH,       0x40),
  DE(OFF_Q2,        0x8B), DE(OFF_H2 + 256,  0x2C),
  DE(OFF_XQR,       0x80), DE(OFF_H2 + 256,  0x00), DE(OFF_Q2 + 256,  0x00),
  DE(OFF_XQR,       0xC0), DE(OFF_Q2 + 256,  0x4A), DE(OFF_XFH,       0x40),
  DE(OFF_Q2 + 256,  0x83), DE(OFF_H2,        0x04),
  DE(OFF_H2,        0x80), DE(OFF_Q2,        0x05),
  DE(OFF_XO,        0x86), DE(OFF_XO,        0x87)};

// load one K-quarter slice (32 VGPRs) for this lane's col
#define ISSQ(BUF, P, CG) {                                                    \
    const u32* gp_ = pan_lane + (((P) << 15) + ((CG) << 13));                 \
    _Pragma("unroll")                                                         \
    for (int r_ = 0; r_ < 8; ++r_) BUF[r_] = *(const u32x4*)(gp_ + (r_ << 8)); \
    SB(); }

__device__ __forceinline__ float cq(const u32x4 (&buf)[8], const float* xp) {
  float a = 0.f;
#pragma unroll
  for (int r = 0; r < 8; ++r) {
    const u32x4 wv = buf[r];
    const f32x4 x0 = *(const f32x4*)(xp + r * 8);
    const f32x4 x1 = *(const f32x4*)(xp + r * 8 + 4);
    a = fmaf(flo(wv[0]), x0[0], a); a = fmaf(fhi(wv[0]), x0[1], a);
    a = fmaf(flo(wv[1]), x0[2], a); a = fmaf(fhi(wv[1]), x0[3], a);
    a = fmaf(flo(wv[2]), x1[0], a); a = fmaf(fhi(wv[2]), x1[1], a);
    a = fmaf(flo(wv[3]), x1[2], a); a = fmaf(fhi(wv[3]), x1[3], a);
  }
  return a;
}

__device__ __forceinline__ void qres_phase(u32* lds, int w8, int col) {
  float qr = 0.f;
  const u32* sp = lds + OFF_SREPT + col * 36;
  const float* ap = (const float*)(lds + OFF_ATTW) + (w8 << 6);
#pragma unroll
  for (int nq = 0; nq < 8; ++nq) {
    const u32x4 sv = *(const u32x4*)(sp + (nq << 2));
    const f32x4 a0 = *(const f32x4*)(ap + (nq << 3));
    const f32x4 a1 = *(const f32x4*)(ap + (nq << 3) + 4);
    qr = fmaf(a0[0], flo(sv[0]), qr); qr = fmaf(a0[1], fhi(sv[0]), qr);
    qr = fmaf(a0[2], flo(sv[1]), qr); qr = fmaf(a0[3], fhi(sv[1]), qr);
    qr = fmaf(a1[0], flo(sv[2]), qr); qr = fmaf(a1[1], fhi(sv[2]), qr);
    qr = fmaf(a1[2], flo(sv[3]), qr); qr = fmaf(a1[3], fhi(sv[3]), qr);
  }
  ((float*)(lds + OFF_XQR))[col] = qr;
}

__device__ __forceinline__ void logits_phase(u32* lds, int w8, int l,
                                             float mk, int cp) {
  float la = 0.f;
  const u32* kp = lds + OFF_SKEY + l * 132;
  const float* qp = (const float*)(lds + OFF_Q2 + cp * 256);
#pragma unroll
  for (int kq = 0; kq < 32; ++kq) {
    const u32x4 kv = *(const u32x4*)(kp + ((kq << 2) ^ ((l & 7) << 2)));
    const f32x4 q0 = *(const f32x4*)(qp + (kq << 3));
    const f32x4 q1 = *(const f32x4*)(qp + (kq << 3) + 4);
    la = fmaf(flo(kv[0]), q0[0], la); la = fmaf(fhi(kv[0]), q0[1], la);
    la = fmaf(flo(kv[1]), q0[2], la); la = fmaf(fhi(kv[1]), q0[3], la);
    la = fmaf(flo(kv[2]), q1[0], la); la = fmaf(fhi(kv[2]), q1[1], la);
    la = fmaf(flo(kv[3]), q1[2], la); la = fmaf(fhi(kv[3]), q1[3], la);
  }
  float mx = la;
#pragma unroll
  for (int o = 1; o < 64; o <<= 1) mx = fmaxf(mx, __shfl_xor(mx, o, 64));
  const float e = __expf(la - mx) * mk;
  float sm = e;
#pragma unroll
  for (int o = 1; o < 64; o <<= 1) sm += __shfl_xor(sm, o, 64);
  ((float*)(lds + OFF_ATTW))[(w8 << 6) + l] = e / sm;
}

__global__ __launch_bounds__(512) void dagsage_main(
    const float* __restrict__ adj,
    const float* __restrict__ b_srep, const float* __restrict__ b_skey,
    const float* __restrict__ pf, const float* __restrict__ ph,
    const float* __restrict__ pq, const float* __restrict__ po,
    const u16* __restrict__ panels,
    float* __restrict__ outp) {
  __shared__ u32 lds[LDS_U32];
  const int t = threadIdx.x;
  const int w8 = t >> 6, l = t & 63;
  const int g = t >> 8;            // K-half (wave-uniform: waves 0-3 / 4-7)
  const int col = t & 255;
  const int w4 = w8 & 3;
  const int q0 = g << 1;           // first K-quarter of my half
  const int b = blockIdx.x;

  // ---- init srepT / skey (out_nodes==0 -> rows are biases) ----
  {
    const float bs0 = b_srep[col];
    for (int j = g * 16; j < g * 16 + 16; ++j)
      lds[OFF_SREPT + col * 36 + j] = pk2f(bs0, bs0);
    const int n = t >> 3, kk0 = (t & 7) * 16;
    for (int j = 0; j < 16; ++j) {
      const int kk = kk0 + j;
      lds[OFF_SKEY + n * 132 + (kk ^ ((n & 7) << 2))] =
          pk2f(b_skey[2 * kk], b_skey[2 * kk + 1]);
    }
  }
  __syncthreads();

  const float bsv = b_srep[col];
  const float bkv = b_skey[col];
  const u32* pan_lane = (const u32*)panels + (w4 << 11) + (l << 2);

  u32x4 bufA[8], bufB[8];
  ISSQ(bufA, PID_F1, q0);   // prologue: F1, my first quarter

#pragma unroll 1
  for (int i = 0; i < 64; ++i) {
    const int ro = (b * 64 + i) * 256 + col;
    float pfv = 0.f, phv = 0.f, pqv = 0.f, pov = 0.f;
    if (!g) { pfv = pf[ro]; phv = ph[ro]; pqv = pq[ro]; pov = po[ro]; }
    const float mk = adj[(b * 64 + l) * 64 + i];

    // it0 attention weights (per-wave copy): attw = mk / sum(mk)
    {
      float sm = mk;
#pragma unroll
      for (int o = 1; o < 64; o <<= 1) sm += __shfl_xor(sm, o, 64);
      ((float*)(lds + OFF_ATTW))[(w8 << 6) + l] = mk / sm;
    }
    qres_phase(lds, w8, col);   // both halves write identical value
    BAR();

    float a0 = 0.f, a1 = 0.f, frv = 0.f, fhv = 0.f;

#pragma unroll 1
    for (int it = 0; it < 23; ++it) {
      const u32 cur = ITBL[it];
      const u32 d = cur >> 16;
      const float* xp = (const float*)(lds + (cur & 0xFFFF));
      const int pc = pid_of(it);
      const int pn = pid_of(it + 1);

      float acc;
      ISSQ(bufB, pc, q0 + 1); acc  = cq(bufA, xp + (q0 << 6));      SB();
      ISSQ(bufA, pn, q0);     acc += cq(bufB, xp + (q0 << 6) + 64); SB();

      if (d & 0x80) { if (d & 0x40) a1 = acc;  else a0 = acc; }
      else          { if (d & 0x40) a1 += acc; else a0 += acc; }

      const int tl = d & 7;
      if (tl) {
        const int p = (d >> 3) & 1;
        const bool ra1 = (tl == 1) | (tl == 3);
        const bool ra0 = (tl != 3);
        if (g) {   // wave-uniform: high half publishes its partials
          if (tl == 6)      ((float*)(lds + OFF_REDB))[col] = a0;
          else {
            if (ra0) ((float*)(lds + OFF_REDA))[col] = a0;
            if (ra1) ((float*)(lds + OFF_REDB))[col] = a1;
          }
        }
        BAR();     // reduce barrier
        if (!g) {
          float A0 = a0, A1 = a1;
          if (tl == 6)      A0 += ((const float*)(lds + OFF_REDB))[col];
          else {
            if (ra0) A0 += ((const float*)(lds + OFF_REDA))[col];
            if (ra1) A1 += ((const float*)(lds + OFF_REDB))[col];
          }
          switch (tl) {
            case 1: {  // FH0
              frv = sgm(A0 + pfv);
              ((float*)(lds + OFF_H2))[col] = (1.f - frv) * tnh(A1 + phv);
            } break;
            case 2: {  // F
              frv = sgm(A0 + pfv);
              fhv = frv * ((const float*)(lds + OFF_H2))[p * 256 + col];
              ((float*)(lds + OFF_XFH))[col] = fhv;
            } break;
            case 3: {  // H
              ((float*)(lds + OFF_H2))[p * 256 + col] =
                  fhv + (1.f - frv) * tnh(A1 + phv);
            } break;
            case 4: {  // Q
              ((float*)(lds + OFF_Q2))[p * 256 + col] = A0 + pqv;
            } break;
            case 5: {  // O
              const float ov = A0 + pov;
              outp[ro] = ov;
              ((float*)(lds + OFF_XO))[col] = ov;
            } break;
            case 6: {  // SR row i (own col; no trailing barrier needed)
              ((u16*)(lds + OFF_SREPT))[col * 72 + i] = f16b(A0 + bsv);
            } break;
            case 7: {  // SK row i
              ((u16*)(lds + OFF_SKEY))[i * 264 + (col ^ ((i & 7) << 3))] =
                  f16b(A0 + bkv);
            } break;
            default: break;
          }
        }
        if (tl != 6) BAR();
        if ((tl == 4) && (d & 0x20)) {   // attention for next iteration
          logits_phase(lds, w8, l, mk, p);
          qres_phase(lds, w8, col);
          BAR();
        }
      }
    }
  }
}

// ---------------------------------------------------------------------------
extern "C" void kernel_launch(void* const* d_in, const int* in_sizes, int n_in,
                              void* d_out, int out_size, void* d_ws, size_t ws_size,
                              hipStream_t stream) {
  const float* nodes    = (const float*)d_in[0];
  const float* adj      = (const float*)d_in[1];
  const float* W_self   = (const float*)d_in[2];
  const float* b_self   = (const float*)d_in[3];
  const float* W_srep   = (const float*)d_in[4];
  const float* b_srep   = (const float*)d_in[5];
  const float* W_skey   = (const float*)d_in[6];
  const float* b_skey   = (const float*)d_in[7];
  const float* W_forget = (const float*)d_in[8];
  const float* b_forget = (const float*)d_in[9];
  const float* W_hid    = (const float*)d_in[10];
  const float* b_hid    = (const float*)d_in[11];
  const float* W_query  = (const float*)d_in[12];
  const float* b_query  = (const float*)d_in[13];
  const float* W_out    = (const float*)d_in[14];
  const float* b_out    = (const float*)d_in[15];
  float* out = (float*)d_out;

  float* rep = (float*)d_ws;
  float* pf = rep + 524288;
  float* ph = pf + 524288;
  float* pq = ph + 524288;
  float* po = pq + 524288;
  u16* panels = (u16*)(po + 524288);

  hipMemcpyAsync(out + 524288, adj, 131072 * sizeof(float),
                 hipMemcpyDeviceToDevice, stream);

  C12 ca;
  ca.src[0]  = W_forget;             // F1  (rows 0:256   <- query_res)
  ca.src[1]  = W_forget + 256 * 256; // F2  (rows 256:512 <- hidden)
  ca.src[2]  = W_forget + 768 * 256; // F4  (rows 768:1024<- query)
  ca.src[3]  = W_hid;                // H1
  ca.src[4]  = W_hid + 256 * 256;    // H2  (<- forget*hidden)
  ca.src[5]  = W_hid + 768 * 256;    // H4
  ca.src[6]  = W_query;              // Q1  (rows 0:256 <- hidden)
  ca.src[7]  = W_query + 512 * 256;  // Q3  (rows 512:768 <- query)
  ca.src[8]  = W_out;                // O1
  ca.src[9]  = W_out + 512 * 256;    // O3
  ca.src[10] = W_srep;               // SR
  ca.src[11] = W_skey;               // SK
  cvt_panels<<<dim3(256, 12), 256, 0, stream>>>(ca, panels);

  G4 g1;
  for (int j = 0; j < 4; ++j) { g1.Bm[j] = W_self; g1.bias[j] = b_self; g1.C[j] = rep; }
  gemm16<<<dim3(128, 1), 256, 0, stream>>>(nodes, g1);

  G4 g2;
  g2.Bm[0] = W_forget + 512 * 256; g2.bias[0] = b_forget; g2.C[0] = pf;
  g2.Bm[1] = W_hid + 512 * 256;    g2.bias[1] = b_hid;    g2.C[1] = ph;
  g2.Bm[2] = W_query + 256 * 256;  g2.bias[2] = b_query;  g2.C[2] = pq;
  g2.Bm[3] = W_out + 256 * 256;    g2.bias[3] = b_out;    g2.C[3] = po;
  gemm16<<<dim3(128, 4), 256, 0, stream>>>(rep, g2);

  dagsage_main<<<32, 512, 0, stream>>>(adj, b_srep, b_skey,
                                       pf, ph, pq, po, panels, out);
}

// Round 14
// 2111.670 us; speedup vs baseline: 9.2348x; 1.2890x over previous
//
#include <hip/hip_runtime.h>
#include <hip/hip_bf16.h>

typedef unsigned int u32;
typedef unsigned short u16;
typedef u32 u32x4 __attribute__((ext_vector_type(4)));
typedef _Float16 h16x2 __attribute__((ext_vector_type(2)));

// ---------------------------------------------------------------------------
// B=32, N=64, R=256. 32 WGs x 512 threads, 1 batch/WG.
// Thread: col = w8*32 + (l&31), K-half g = l>>5  (IN-WAVE K-split).
//
// ROUND-13 LESSON: cross-wave K-split doubled barriers (~30/step) and
// serialized tails on half the block -> only +11%. THIS ROUND: in-wave
// K-split (cross-half reduce = shfl_xor(,32), no LDS scratch, no reduce
// barriers; tails uniform on all lanes) + v_dot2_f32_f16 packed-f16 state
// (halves FMA inst count) + broadcast x reads. ~12 barriers/step.
//
// Panel u16 layout: e = pid*65536 + w8*8192 + c*4096 + r*512 + l*8 + j
//   -> col = w8*32 + (l&31), K = (2*(l>>5)+c)*64 + r*8 + j.
// Per (wave, c, r): 64 lanes x 16B = 1KB contiguous (perfect coalescing).
// ---------------------------------------------------------------------------

struct G4 { const float* Bm[4]; const float* bias[4]; float* C[4]; };

__global__ __launch_bounds__(256) void gemm16(const float* __restrict__ A, G4 g) {
  __shared__ float At[16 * 256];
  const int sub = blockIdx.y;
  const float* __restrict__ Bm = g.Bm[sub];
  const float* __restrict__ bias = g.bias[sub];
  float* __restrict__ C = g.C[sub];
  const int r0 = blockIdx.x * 16;
  const int t = threadIdx.x;
#pragma unroll
  for (int j = 0; j < 16; ++j) At[j * 256 + t] = A[(r0 + j) * 256 + t];
  __syncthreads();
  float acc[16];
#pragma unroll
  for (int j = 0; j < 16; ++j) acc[j] = 0.f;
  for (int k = 0; k < 256; ++k) {
    const float bv = Bm[k * 256 + t];
#pragma unroll
    for (int j = 0; j < 16; ++j) acc[j] = fmaf(At[j * 256 + k], bv, acc[j]);
  }
  const float bs = bias[t];
#pragma unroll
  for (int j = 0; j < 16; ++j) C[(r0 + j) * 256 + t] = acc[j] + bs;
}

struct C12 { const float* src[12]; };

__device__ __forceinline__ u16 f16b(float x) {
  union { _Float16 h; u16 u; } c; c.h = (_Float16)x; return c.u;
}
__device__ __forceinline__ u32 pk2f(float a, float b) {
  return (u32)f16b(a) | ((u32)f16b(b) << 16);
}
__device__ __forceinline__ float f16f(u16 x) {
  union { u16 u; _Float16 h; } c; c.u = x; return (float)c.h;
}
__device__ __forceinline__ h16x2 ash2(u32 x) {
  union { u32 u; h16x2 h; } c; c.u = x; return c.h;
}

#if __has_builtin(__builtin_amdgcn_fdot2)
#define FDOT2(A, W, X) A = __builtin_amdgcn_fdot2(ash2(W), ash2(X), A, false)
#else
#define FDOT2(A, W, X) \
  asm("v_dot2_f32_f16 %0, %1, %2, %0" : "+v"(A) : "v"(W), "v"(X))
#endif

__global__ __launch_bounds__(256) void cvt_panels(C12 c, u16* __restrict__ dst) {
  const int z = blockIdx.y;
  const float* __restrict__ in = c.src[z];
  const int e = blockIdx.x * 256 + threadIdx.x;   // [0, 65536)
  const int j = e & 7, l = (e >> 3) & 63, r = (e >> 9) & 7;
  const int cc = (e >> 12) & 1, w8 = e >> 13;
  const int col = w8 * 32 + (l & 31);
  const int k = (2 * (l >> 5) + cc) * 64 + r * 8 + j;
  dst[z * 65536 + e] = f16b(in[k * 256 + col]);
}

// ---------------- main kernel --------------------------------------------
#define PID_F1 0

// LDS offsets (u32 units); all x-state packed f16 (2 per u32)
#define OFF_SREPT 0       // [256 cols][36] u32 (64 nodes f16 + pad)
#define OFF_SKEY  9216    // [64 nodes][132] u32 (256 k f16, XOR-swz)
#define OFF_ATTW  17664   // [8 waves][32] u32 (64 nodes f16)
#define OFF_XQR   17920   // [128] u32 (256 cols f16)
#define OFF_XFH   18048
#define OFF_XO    18176
#define OFF_H2    18304   // [2][128]
#define OFF_Q2    18560   // [2][128]
#define LDS_U32   18816   // 75,264 B

#define BAR() asm volatile("s_waitcnt lgkmcnt(0)\n\ts_barrier" ::: "memory")
#define SB()  __builtin_amdgcn_sched_barrier(0)

__device__ __forceinline__ float sgm(float x) { return 1.f / (1.f + __expf(-x)); }
__device__ __forceinline__ float tnh(float x) { return 1.f - 2.f / (__expf(2.f * x) + 1.f); }

// item pids: F1,H1,Q1 | F1,F2,F4,H1,H4,H2,Q3,Q1 | x2 | O1,O3,SR,SK | F1(wrap)
__device__ __forceinline__ int pid_of(int idx) {
  const unsigned long long P0 = 0x5321067453210630ull;   // idx 0..15
  const unsigned long long P1 = 0x000000000BA98674ull;   // idx 16..23
  const unsigned long long v = (idx < 16) ? (P0 >> (idx * 4))
                                          : (P1 >> ((idx - 16) * 4));
  return (int)(v & 15);
}

// desc: tail(0..7) | p<<3 | att<<5 | asel<<6 | reset<<7 ; entry = xoff|desc<<16
#define DE(x, d) ((u32)(x) | ((u32)(d) << 16))
__device__ const u32 ITBL[23] = {
  DE(OFF_XQR,       0x80), DE(OFF_XQR,       0xC1), DE(OFF_H2,        0xA4),
  DE(OFF_XQR,       0x80), DE(OFF_H2,        0x00), DE(OFF_Q2,        0x00),
  DE(OFF_XQR,       0xC0), DE(OFF_Q2,        0x42), DE(OFF_XFH,       0x40),
  DE(OFF_Q2,        0x8B), DE(OFF_H2 + 128,  0x2C),
  DE(OFF_XQR,       0x80), DE(OFF_H2 + 128,  0x00), DE(OFF_Q2 + 128,  0x00),
  DE(OFF_XQR,       0xC0), DE(OFF_Q2 + 128,  0x4A), DE(OFF_XFH,       0x40),
  DE(OFF_Q2 + 128,  0x83), DE(OFF_H2,        0x04),
  DE(OFF_H2,        0x80), DE(OFF_Q2,        0x05),
  DE(OFF_XO,        0x86), DE(OFF_XO,        0x87)};

// load one K-quarter slice (8x16B = 64 f16 = 32 VGPRs) for this thread
#define ISSQ(BUF, P, C) {                                                     \
    const u32* gp_ = pan_lane + (((P) << 15) + ((C) << 11));                  \
    _Pragma("unroll")                                                         \
    for (int r_ = 0; r_ < 8; ++r_) BUF[r_] = *(const u32x4*)(gp_ + (r_ << 8)); \
    SB(); }

// one quarter: 32 fdot2 (64 MACs); xq = packed x for this quarter (32 u32)
__device__ __forceinline__ float cq(const u32x4 (&buf)[8], const u32* xq) {
  float a = 0.f;
#pragma unroll
  for (int r = 0; r < 8; ++r) {
    const u32x4 wv = buf[r];
    const u32x4 xv = *(const u32x4*)(xq + (r << 2));
    FDOT2(a, wv[0], xv[0]); FDOT2(a, wv[1], xv[1]);
    FDOT2(a, wv[2], xv[2]); FDOT2(a, wv[3], xv[3]);
  }
  return a;
}

__device__ __forceinline__ void qres_phase(u32* lds, int w8, int col) {
  float qr = 0.f;
  const u32* sp = lds + OFF_SREPT + col * 36;
  const u32* ap = lds + OFF_ATTW + (w8 << 5);
#pragma unroll
  for (int nq = 0; nq < 8; ++nq) {
    const u32x4 sv = *(const u32x4*)(sp + (nq << 2));
    const u32x4 av = *(const u32x4*)(ap + (nq << 2));
    FDOT2(qr, sv[0], av[0]); FDOT2(qr, sv[1], av[1]);
    FDOT2(qr, sv[2], av[2]); FDOT2(qr, sv[3], av[3]);
  }
  ((u16*)(lds + OFF_XQR))[col] = f16b(qr);
}

__device__ __forceinline__ void logits_phase(u32* lds, int w8, int l,
                                             float mk, int cp) {
  float la = 0.f;
  const u32* kp = lds + OFF_SKEY + l * 132;
  const u32* qp = lds + OFF_Q2 + cp * 128;
#pragma unroll
  for (int kq = 0; kq < 32; ++kq) {
    const u32x4 kv = *(const u32x4*)(kp + (((u32)(kq << 2)) ^ ((l & 7) << 2)));
    const u32x4 qv = *(const u32x4*)(qp + (kq << 2));
    FDOT2(la, kv[0], qv[0]); FDOT2(la, kv[1], qv[1]);
    FDOT2(la, kv[2], qv[2]); FDOT2(la, kv[3], qv[3]);
  }
  float mx = la;
#pragma unroll
  for (int o = 1; o < 64; o <<= 1) mx = fmaxf(mx, __shfl_xor(mx, o, 64));
  const float e = __expf(la - mx) * mk;
  float sm = e;
#pragma unroll
  for (int o = 1; o < 64; o <<= 1) sm += __shfl_xor(sm, o, 64);
  ((u16*)(lds + OFF_ATTW))[(w8 << 6) + l] = f16b(e / sm);
}

__global__ __launch_bounds__(512) void dagsage_main(
    const float* __restrict__ adj,
    const float* __restrict__ b_srep, const float* __restrict__ b_skey,
    const float* __restrict__ pf, const float* __restrict__ ph,
    const float* __restrict__ pq, const float* __restrict__ po,
    const u16* __restrict__ panels,
    float* __restrict__ outp) {
  __shared__ u32 lds[LDS_U32];
  const int t = threadIdx.x;
  const int w8 = t >> 6, l = t & 63;
  const int g = l >> 5;                 // in-wave K-half
  const int col = (w8 << 5) + (l & 31);
  const int xq0 = g << 6;               // u32 offset of my half's 2 quarters
  const int b = blockIdx.x;

  // ---- init srepT / skey (out_nodes==0 -> rows are biases) ----
  {
    const float bs0 = b_srep[col];
    for (int j = g * 16; j < g * 16 + 16; ++j)
      lds[OFF_SREPT + col * 36 + j] = pk2f(bs0, bs0);
    const int n = t >> 3, kk0 = (t & 7) * 16;
    for (int j = 0; j < 16; ++j) {
      const int kk = kk0 + j;
      lds[OFF_SKEY + n * 132 + (((u32)kk) ^ ((n & 7) << 2))] =
          pk2f(b_skey[2 * kk], b_skey[2 * kk + 1]);
    }
  }
  __syncthreads();

  const float bsv = b_srep[col];
  const float bkv = b_skey[col];
  const u32* pan_lane = (const u32*)panels + (w8 << 12) + (l << 2);

  u32x4 bufA[8], bufB[8];
  ISSQ(bufA, PID_F1, 0);   // prologue: F1, my half's first quarter

#pragma unroll 1
  for (int i = 0; i < 64; ++i) {
    const int ro = (b * 64 + i) * 256 + col;
    const float pfv = pf[ro], phv = ph[ro], pqv = pq[ro], pov = po[ro];
    const float mk = adj[(b * 64 + l) * 64 + i];

    // it0 attention weights (per-wave copy): attw = mk / sum(mk)
    {
      float sm = mk;
#pragma unroll
      for (int o = 1; o < 64; o <<= 1) sm += __shfl_xor(sm, o, 64);
      ((u16*)(lds + OFF_ATTW))[(w8 << 6) + l] = f16b(mk / sm);
    }
    qres_phase(lds, w8, col);
    BAR();

    float a0 = 0.f, a1 = 0.f, frv = 0.f, fhv = 0.f;

#pragma unroll 1
    for (int it = 0; it < 23; ++it) {
      const u32 cur = ITBL[it];
      const u32 d = cur >> 16;
      const u32* xq = lds + (cur & 0xFFFF) + xq0;
      const int pc = pid_of(it);
      const int pn = pid_of(it + 1);

      float acc;
      ISSQ(bufB, pc, 1); acc  = cq(bufA, xq);      SB();
      ISSQ(bufA, pn, 0); acc += cq(bufB, xq + 32); SB();

      if (d & 0x80) { if (d & 0x40) a1 = acc;  else a0 = acc; }
      else          { if (d & 0x40) a1 += acc; else a0 += acc; }

      const int tl = d & 7;
      if (tl) {
        const int p = (d >> 3) & 1;
        const float A0 = a0 + __shfl_xor(a0, 32, 64);
        const float A1 = a1 + __shfl_xor(a1, 32, 64);
        // all lanes compute tails; both K-halves write identical values
        switch (tl) {
          case 1: {  // FH0
            frv = sgm(A0 + pfv);
            ((u16*)(lds + OFF_H2))[col] = f16b((1.f - frv) * tnh(A1 + phv));
          } break;
          case 2: {  // F
            frv = sgm(A0 + pfv);
            fhv = frv * f16f(((const u16*)(lds + OFF_H2))[p * 256 + col]);
            ((u16*)(lds + OFF_XFH))[col] = f16b(fhv);
          } break;
          case 3: {  // H
            ((u16*)(lds + OFF_H2))[p * 256 + col] =
                f16b(fhv + (1.f - frv) * tnh(A1 + phv));
          } break;
          case 4: {  // Q
            ((u16*)(lds + OFF_Q2))[p * 256 + col] = f16b(A0 + pqv);
          } break;
          case 5: {  // O
            const float ov = A0 + pov;
            if (l < 32) outp[ro] = ov;
            ((u16*)(lds + OFF_XO))[col] = f16b(ov);
          } break;
          case 6: {  // SR: srep row i (own col; no barrier needed)
            ((u16*)(lds + OFF_SREPT))[col * 72 + i] = f16b(A0 + bsv);
          } break;
          case 7: {  // SK: skey row i (consumed after next step's barriers)
            ((u16*)(lds + OFF_SKEY))[i * 264 + (((u32)col) ^ ((i & 7) << 3))] =
                f16b(A0 + bkv);
          } break;
          default: break;
        }
        if (tl < 6) BAR();
        if ((tl == 4) && (d & 0x20)) {   // attention for next iteration
          logits_phase(lds, w8, l, mk, p);
          qres_phase(lds, w8, col);
          BAR();
        }
      }
    }
  }
}

// ---------------------------------------------------------------------------
extern "C" void kernel_launch(void* const* d_in, const int* in_sizes, int n_in,
                              void* d_out, int out_size, void* d_ws, size_t ws_size,
                              hipStream_t stream) {
  const float* nodes    = (const float*)d_in[0];
  const float* adj      = (const float*)d_in[1];
  const float* W_self   = (const float*)d_in[2];
  const float* b_self   = (const float*)d_in[3];
  const float* W_srep   = (const float*)d_in[4];
  const float* b_srep   = (const float*)d_in[5];
  const float* W_skey   = (const float*)d_in[6];
  const float* b_skey   = (const float*)d_in[7];
  const float* W_forget = (const float*)d_in[8];
  const float* b_forget = (const float*)d_in[9];
  const float* W_hid    = (const float*)d_in[10];
  const float* b_hid    = (const float*)d_in[11];
  const float* W_query  = (const float*)d_in[12];
  const float* b_query  = (const float*)d_in[13];
  const float* W_out    = (const float*)d_in[14];
  const float* b_out    = (const float*)d_in[15];
  float* out = (float*)d_out;

  float* rep = (float*)d_ws;
  float* pf = rep + 524288;
  float* ph = pf + 524288;
  float* pq = ph + 524288;
  float* po = pq + 524288;
  u16* panels = (u16*)(po + 524288);

  hipMemcpyAsync(out + 524288, adj, 131072 * sizeof(float),
                 hipMemcpyDeviceToDevice, stream);

  C12 ca;
  ca.src[0]  = W_forget;             // F1  (rows 0:256   <- query_res)
  ca.src[1]  = W_forget + 256 * 256; // F2  (rows 256:512 <- hidden)
  ca.src[2]  = W_forget + 768 * 256; // F4  (rows 768:1024<- query)
  ca.src[3]  = W_hid;                // H1
  ca.src[4]  = W_hid + 256 * 256;    // H2  (<- forget*hidden)
  ca.src[5]  = W_hid + 768 * 256;    // H4
  ca.src[6]  = W_query;              // Q1  (rows 0:256 <- hidden)
  ca.src[7]  = W_query + 512 * 256;  // Q3  (rows 512:768 <- query)
  ca.src[8]  = W_out;                // O1
  ca.src[9]  = W_out + 512 * 256;    // O3
  ca.src[10] = W_srep;               // SR
  ca.src[11] = W_skey;               // SK
  cvt_panels<<<dim3(256, 12), 256, 0, stream>>>(ca, panels);

  G4 g1;
  for (int j = 0; j < 4; ++j) { g1.Bm[j] = W_self; g1.bias[j] = b_self; g1.C[j] = rep; }
  gemm16<<<dim3(128, 1), 256, 0, stream>>>(nodes, g1);

  G4 g2;
  g2.Bm[0] = W_forget + 512 * 256; g2.bias[0] = b_forget; g2.C[0] = pf;
  g2.Bm[1] = W_hid + 512 * 256;    g2.bias[1] = b_hid;    g2.C[1] = ph;
  g2.Bm[2] = W_query + 256 * 256;  g2.bias[2] = b_query;  g2.C[2] = pq;
  g2.Bm[3] = W_out + 256 * 256;    g2.bias[3] = b_out;    g2.C[3] = po;
  gemm16<<<dim3(128, 4), 256, 0, stream>>>(rep, g2);

  dagsage_main<<<32, 512, 0, stream>>>(adj, b_srep, b_skey,
                                       pf, ph, pq, po, panels, out);
}

// Round 17
// 2058.329 us; speedup vs baseline: 9.4741x; 1.0259x over previous
//
#include <hip/hip_runtime.h>
#include <hip/hip_bf16.h>

typedef unsigned int u32;
typedef unsigned short u16;
typedef u32 u32x4 __attribute__((ext_vector_type(4)));
typedef _Float16 h16x2 __attribute__((ext_vector_type(2)));

// ---------------------------------------------------------------------------
// B=32, N=64, R=256. 32 WGs x 512 threads, 1 batch/WG.
// Thread: col = w8*32 + (l&31), K-half g = l>>5 (in-wave K-split).
//
// ROUND-16 LESSON: the Z-trick refactor failed twice (NaN, then 0.44);
// reverted to the verified round-14 kernel (2.11ms, absmax 0.0156) and
// applied ONLY the out-fold: out = h3@(O1+Q1@O3) + q2@(Q3@O3) + (po+pq@O3).
// Prep computes A=O1+Q1@O3, B=Q3@O3 (f32 GEMMs), poO=po+pq@O3. Main loop:
// it2's Q3/Q1 items removed (q3 never materialized), h3-tail moved onto the
// H2 item; panels 8/9 now hold A/B instead of O1/O3. 23 -> 21 items.
//
// Panel u16 layout: e = pid*65536 + w8*8192 + c*4096 + r*512 + l*8 + j
//   -> col = w8*32+(l&31), K = (2*(l>>5)+c)*64 + r*8 + j.
// ---------------------------------------------------------------------------

struct G4 { const float* Bm[4]; const float* bias[4]; float* C[4]; };

__global__ __launch_bounds__(256) void gemm16(const float* __restrict__ A, G4 g) {
  __shared__ float At[16 * 256];
  const int sub = blockIdx.y;
  const float* __restrict__ Bm = g.Bm[sub];
  const float* __restrict__ bias = g.bias[sub];
  float* __restrict__ C = g.C[sub];
  const int r0 = blockIdx.x * 16;
  const int t = threadIdx.x;
#pragma unroll
  for (int j = 0; j < 16; ++j) At[j * 256 + t] = A[(r0 + j) * 256 + t];
  __syncthreads();
  float acc[16];
#pragma unroll
  for (int j = 0; j < 16; ++j) acc[j] = 0.f;
  for (int k = 0; k < 256; ++k) {
    const float bv = Bm[k * 256 + t];
#pragma unroll
    for (int j = 0; j < 16; ++j) acc[j] = fmaf(At[j * 256 + k], bv, acc[j]);
  }
  const float bs = bias[t];
#pragma unroll
  for (int j = 0; j < 16; ++j) C[(r0 + j) * 256 + t] = acc[j] + bs;
}

// C = A@B (+D); rows = gridDim.x*16
__global__ __launch_bounds__(256) void gemmD(const float* __restrict__ A,
                                             const float* __restrict__ B,
                                             const float* __restrict__ D,
                                             float* __restrict__ C) {
  __shared__ float At[16 * 256];
  const int r0 = blockIdx.x * 16;
  const int t = threadIdx.x;
#pragma unroll
  for (int j = 0; j < 16; ++j) At[j * 256 + t] = A[(r0 + j) * 256 + t];
  __syncthreads();
  float acc[16];
#pragma unroll
  for (int j = 0; j < 16; ++j) acc[j] = 0.f;
  for (int k = 0; k < 256; ++k) {
    const float bv = B[k * 256 + t];
#pragma unroll
    for (int j = 0; j < 16; ++j) acc[j] = fmaf(At[j * 256 + k], bv, acc[j]);
  }
#pragma unroll
  for (int j = 0; j < 16; ++j) {
    const float dv = D ? D[(r0 + j) * 256 + t] : 0.f;
    C[(r0 + j) * 256 + t] = acc[j] + dv;
  }
}

struct C12 { const float* src[12]; };

__device__ __forceinline__ u16 f16b(float x) {
  union { _Float16 h; u16 u; } c; c.h = (_Float16)x; return c.u;
}
__device__ __forceinline__ u32 pk2f(float a, float b) {
  return (u32)f16b(a) | ((u32)f16b(b) << 16);
}
__device__ __forceinline__ float f16f(u16 x) {
  union { u16 u; _Float16 h; } c; c.u = x; return (float)c.h;
}
__device__ __forceinline__ h16x2 ash2(u32 x) {
  union { u32 u; h16x2 h; } c; c.u = x; return c.h;
}

#if __has_builtin(__builtin_amdgcn_fdot2)
#define FDOT2(A, W, X) A = __builtin_amdgcn_fdot2(ash2(W), ash2(X), A, false)
#else
#define FDOT2(A, W, X) \
  asm("v_dot2_f32_f16 %0, %1, %2, %0" : "+v"(A) : "v"(W), "v"(X))
#endif

__global__ __launch_bounds__(256) void cvt_panels(C12 c, u16* __restrict__ dst) {
  const int z = blockIdx.y;
  const float* __restrict__ in = c.src[z];
  const int e = blockIdx.x * 256 + threadIdx.x;   // [0, 65536)
  const int j = e & 7, l = (e >> 3) & 63, r = (e >> 9) & 7;
  const int cc = (e >> 12) & 1, w8 = e >> 13;
  const int col = w8 * 32 + (l & 31);
  const int k = (2 * (l >> 5) + cc) * 64 + r * 8 + j;
  dst[z * 65536 + e] = f16b(in[k * 256 + col]);
}

// ---------------- main kernel --------------------------------------------
#define PID_F1 0

// LDS offsets (u32 units)
#define OFF_SREPT 0       // [256 cols][36] u32 rows (64 nodes f16 + pad)
#define OFF_SKEY  9216    // [64 nodes][132] u32 rows (256 k f16, XOR-swz)
#define OFF_ATTW  17664   // [8 waves][32] u32 (64 nodes f16)
#define OFF_XQR   17920   // [128] u32 (256 cols f16)
#define OFF_XFH   18048
#define OFF_XO    18176
#define OFF_H2    18304   // [2][128]
#define OFF_Q2    18560   // [2][128]
#define LDS_U32   18816   // 75,264 B

#define BAR() asm volatile("s_waitcnt lgkmcnt(0)\n\ts_barrier" ::: "memory")
#define SB()  __builtin_amdgcn_sched_barrier(0)

__device__ __forceinline__ float sgm(float x) { return 1.f / (1.f + __expf(-x)); }
__device__ __forceinline__ float tnh(float x) { return 1.f - 2.f / (__expf(2.f * x) + 1.f); }

// item pids (21 + wrap): F1,H1,Q1 | F1,F2,F4,H1,H4,H2,Q3,Q1 | F1,F2,F4,H1,H4,H2
// | A,B,SR,SK | F1.  pid map: 0:F1 1:F2 2:F4 3:H1 4:H2 5:H4 6:Q1 7:Q3 8:A 9:B
// 10:SR 11:SK
__device__ __forceinline__ int pid_of(int idx) {
  const unsigned long long P0 = 0x5321067453210630ull;   // idx 0..15
  const unsigned long long P1 = 0x00000000000BA984ull;   // idx 16..21
  const unsigned long long v = (idx < 16) ? (P0 >> (idx * 4))
                                          : (P1 >> ((idx - 16) * 4));
  return (int)(v & 15);
}

// desc: tail(0..7) | p<<3 | att<<5 | asel<<6 | reset<<7 ; entry = xoff|desc<<16
#define DE(x, d) ((u32)(x) | ((u32)(d) << 16))
__device__ const u32 ITBL[21] = {
  DE(OFF_XQR,       0x80),   //  0 F1@xqr    reset a0
  DE(OFF_XQR,       0xC1),   //  1 H1@xqr    reset a1, tail FH0
  DE(OFF_H2,        0xA4),   //  2 Q1@h1     reset a0, att, tail Q p0
  DE(OFF_XQR,       0x80),   //  3 F1@xqr    reset a0           (it1)
  DE(OFF_H2,        0x00),   //  4 F2@h1
  DE(OFF_Q2,        0x00),   //  5 F4@q1
  DE(OFF_XQR,       0xC0),   //  6 H1@xqr    reset a1
  DE(OFF_Q2,        0x42),   //  7 H4@q1     a1, tail F p0
  DE(OFF_XFH,       0x40),   //  8 H2@fh     a1
  DE(OFF_Q2,        0x8B),   //  9 Q3@q1     reset a0, tail H p1 (h2->slot1)
  DE(OFF_H2 + 128,  0x2C),   // 10 Q1@h2     a0, att, tail Q p1  (q2->slot1)
  DE(OFF_XQR,       0x80),   // 11 F1@xqr    reset a0           (it2)
  DE(OFF_H2 + 128,  0x00),   // 12 F2@h2
  DE(OFF_Q2 + 128,  0x00),   // 13 F4@q2
  DE(OFF_XQR,       0xC0),   // 14 H1@xqr    reset a1
  DE(OFF_Q2 + 128,  0x4A),   // 15 H4@q2     a1, tail F p1
  DE(OFF_XFH,       0x43),   // 16 H2@fh     a1, tail H p0 (h3->slot0)
  DE(OFF_H2,        0x80),   // 17 A@h3      reset a0
  DE(OFF_Q2 + 128,  0x05),   // 18 B@q2      a0, tail O
  DE(OFF_XO,        0x86),   // 19 SR@xo     reset, tail SR
  DE(OFF_XO,        0x87)};  // 20 SK@xo     reset, tail SK (+BAR)

// load one K-quarter slice (8x16B = 64 f16 = 32 VGPRs) for this thread
#define ISSQ(BUF, P, C) {                                                     \
    const u32* gp_ = pan_lane + (((P) << 15) + ((C) << 11));                  \
    _Pragma("unroll")                                                         \
    for (int r_ = 0; r_ < 8; ++r_) BUF[r_] = *(const u32x4*)(gp_ + (r_ << 8)); \
    SB(); }

// one quarter: 32 fdot2 (64 MACs); xq = packed x for this quarter (32 u32)
__device__ __forceinline__ float cq(const u32x4 (&buf)[8], const u32* xq) {
  float a = 0.f;
#pragma unroll
  for (int r = 0; r < 8; ++r) {
    const u32x4 wv = buf[r];
    const u32x4 xv = *(const u32x4*)(xq + (r << 2));
    FDOT2(a, wv[0], xv[0]); FDOT2(a, wv[1], xv[1]);
    FDOT2(a, wv[2], xv[2]); FDOT2(a, wv[3], xv[3]);
  }
  return a;
}

__device__ __forceinline__ void qres_phase(u32* lds, int w8, int col) {
  float qr = 0.f;
  const u32* sp = lds + OFF_SREPT + col * 36;
  const u32* ap = lds + OFF_ATTW + (w8 << 5);
#pragma unroll
  for (int nq = 0; nq < 8; ++nq) {
    const u32x4 sv = *(const u32x4*)(sp + (nq << 2));
    const u32x4 av = *(const u32x4*)(ap + (nq << 2));
    FDOT2(qr, sv[0], av[0]); FDOT2(qr, sv[1], av[1]);
    FDOT2(qr, sv[2], av[2]); FDOT2(qr, sv[3], av[3]);
  }
  ((u16*)(lds + OFF_XQR))[col] = f16b(qr);
}

__device__ __forceinline__ void logits_phase(u32* lds, int w8, int l,
                                             float mk, int cp) {
  float la = 0.f;
  const u32* kp = lds + OFF_SKEY + l * 132;
  const u32* qp = lds + OFF_Q2 + cp * 128;
#pragma unroll
  for (int kq = 0; kq < 32; ++kq) {
    const u32x4 kv = *(const u32x4*)(kp + (((u32)(kq << 2)) ^ ((l & 7) << 2)));
    const u32x4 qv = *(const u32x4*)(qp + (kq << 2));
    FDOT2(la, kv[0], qv[0]); FDOT2(la, kv[1], qv[1]);
    FDOT2(la, kv[2], qv[2]); FDOT2(la, kv[3], qv[3]);
  }
  float mx = la;
#pragma unroll
  for (int o = 1; o < 64; o <<= 1) mx = fmaxf(mx, __shfl_xor(mx, o, 64));
  const float e = __expf(la - mx) * mk;
  float sm = e;
#pragma unroll
  for (int o = 1; o < 64; o <<= 1) sm += __shfl_xor(sm, o, 64);
  ((u16*)(lds + OFF_ATTW))[(w8 << 6) + l] = f16b(e / sm);
}

__global__ __launch_bounds__(512) void dagsage_main(
    const float* __restrict__ adj,
    const float* __restrict__ b_srep, const float* __restrict__ b_skey,
    const float* __restrict__ pf, const float* __restrict__ ph,
    const float* __restrict__ pq, const float* __restrict__ poO,
    const u16* __restrict__ panels,
    float* __restrict__ outp) {
  __shared__ u32 lds[LDS_U32];
  const int t = threadIdx.x;
  const int w8 = t >> 6, l = t & 63;
  const int g = l >> 5;                 // in-wave K-half
  const int col = (w8 << 5) + (l & 31);
  const int xq0 = g << 6;               // u32 offset of my half's 2 quarters
  const int b = blockIdx.x;

  // ---- init srepT / skey (out_nodes==0 -> rows are biases) ----
  {
    const float bs0 = b_srep[col];
    for (int j = g * 16; j < g * 16 + 16; ++j)
      lds[OFF_SREPT + col * 36 + j] = pk2f(bs0, bs0);
    const int n = t >> 3, kk0 = (t & 7) * 16;
    for (int j = 0; j < 16; ++j) {
      const int kk = kk0 + j;
      lds[OFF_SKEY + n * 132 + (((u32)kk) ^ ((n & 7) << 2))] =
          pk2f(b_skey[2 * kk], b_skey[2 * kk + 1]);
    }
  }
  __syncthreads();

  const float bsv = b_srep[col];
  const float bkv = b_skey[col];
  const u32* pan_lane = (const u32*)panels + (w8 << 12) + (l << 2);

  u32x4 bufA[8], bufB[8];
  ISSQ(bufA, PID_F1, 0);   // prologue: F1, my half's first quarter

#pragma unroll 1
  for (int i = 0; i < 64; ++i) {
    const int ro = (b * 64 + i) * 256 + col;
    const float pfv = pf[ro], phv = ph[ro], pqv = pq[ro], pov = poO[ro];
    const float mk = adj[(b * 64 + l) * 64 + i];

    // it0 attention weights (per-wave copy): attw = mk / sum(mk)
    {
      float sm = mk;
#pragma unroll
      for (int o = 1; o < 64; o <<= 1) sm += __shfl_xor(sm, o, 64);
      ((u16*)(lds + OFF_ATTW))[(w8 << 6) + l] = f16b(mk / sm);
    }
    qres_phase(lds, w8, col);
    BAR();

    float a0 = 0.f, a1 = 0.f, frv = 0.f, fhv = 0.f;

#pragma unroll 1
    for (int it = 0; it < 21; ++it) {
      const u32 cur = ITBL[it];
      const u32 d = cur >> 16;
      const u32* xq = lds + (cur & 0xFFFF) + xq0;
      const int pc = pid_of(it);
      const int pn = pid_of(it + 1);

      float acc;
      ISSQ(bufB, pc, 1); acc  = cq(bufA, xq);      SB();
      ISSQ(bufA, pn, 0); acc += cq(bufB, xq + 32); SB();

      if (d & 0x80) { if (d & 0x40) a1 = acc;  else a0 = acc; }
      else          { if (d & 0x40) a1 += acc; else a0 += acc; }

      const int tl = d & 7;
      if (tl) {
        const int p = (d >> 3) & 1;
        const float A0 = a0 + __shfl_xor(a0, 32, 64);
        const float A1 = a1 + __shfl_xor(a1, 32, 64);
        // all lanes compute tails; both K-halves write identical values
        switch (tl) {
          case 1: {  // FH0
            frv = sgm(A0 + pfv);
            ((u16*)(lds + OFF_H2))[col] = f16b((1.f - frv) * tnh(A1 + phv));
          } break;
          case 2: {  // F
            frv = sgm(A0 + pfv);
            fhv = frv * f16f(((const u16*)(lds + OFF_H2))[p * 256 + col]);
            ((u16*)(lds + OFF_XFH))[col] = f16b(fhv);
          } break;
          case 3: {  // H
            ((u16*)(lds + OFF_H2))[p * 256 + col] =
                f16b(fhv + (1.f - frv) * tnh(A1 + phv));
          } break;
          case 4: {  // Q
            ((u16*)(lds + OFF_Q2))[p * 256 + col] = f16b(A0 + pqv);
          } break;
          case 5: {  // O: out = h3@A + q2@B + poO
            const float ov = A0 + pov;
            if (l < 32) outp[ro] = ov;
            ((u16*)(lds + OFF_XO))[col] = f16b(ov);
          } break;
          case 6: {  // SR: srep row i (own col; no barrier needed)
            ((u16*)(lds + OFF_SREPT))[col * 72 + i] = f16b(A0 + bsv);
          } break;
          case 7: {  // SK: skey row i (consumed after next step's barriers)
            ((u16*)(lds + OFF_SKEY))[i * 264 + (((u32)col) ^ ((i & 7) << 3))] =
                f16b(A0 + bkv);
          } break;
          default: break;
        }
        if (tl < 6) BAR();
        if ((tl == 4) && (d & 0x20)) {   // attention for next iteration
          logits_phase(lds, w8, l, mk, p);
          qres_phase(lds, w8, col);
          BAR();
        }
      }
    }
  }
}

// ---------------------------------------------------------------------------
extern "C" void kernel_launch(void* const* d_in, const int* in_sizes, int n_in,
                              void* d_out, int out_size, void* d_ws, size_t ws_size,
                              hipStream_t stream) {
  const float* nodes    = (const float*)d_in[0];
  const float* adj      = (const float*)d_in[1];
  const float* W_self   = (const float*)d_in[2];
  const float* b_self   = (const float*)d_in[3];
  const float* W_srep   = (const float*)d_in[4];
  const float* b_srep   = (const float*)d_in[5];
  const float* W_skey   = (const float*)d_in[6];
  const float* b_skey   = (const float*)d_in[7];
  const float* W_forget = (const float*)d_in[8];
  const float* b_forget = (const float*)d_in[9];
  const float* W_hid    = (const float*)d_in[10];
  const float* b_hid    = (const float*)d_in[11];
  const float* W_query  = (const float*)d_in[12];
  const float* b_query  = (const float*)d_in[13];
  const float* W_out    = (const float*)d_in[14];
  const float* b_out    = (const float*)d_in[15];
  float* out = (float*)d_out;

  float* rep = (float*)d_ws;           // 524288
  float* pf  = rep + 524288;
  float* ph  = pf + 524288;
  float* pq  = ph + 524288;
  float* po  = pq + 524288;            // becomes poO in-place
  u16* panels = (u16*)(po + 524288);   // 12 * 65536 u16
  // temporaries in the pf region BEFORE g2 runs (cvt consumes them first)
  float* tmpA = pf;                    // 65536
  float* tmpB = pf + 65536;

  const float* Q1 = W_query;               // rows 0:256
  const float* O3 = W_out + 512 * 256;

  hipMemcpyAsync(out + 524288, adj, 131072 * sizeof(float),
                 hipMemcpyDeviceToDevice, stream);

  // 1) out-fold precomputes (f32, exact)
  gemmD<<<16, 256, 0, stream>>>(Q1, O3, W_out, tmpA);                // A = Q1@O3 + O1
  gemmD<<<16, 256, 0, stream>>>(W_query + 512 * 256, O3, nullptr, tmpB); // B = Q3@O3

  // 2) convert 12 panels (consumes tmpA/tmpB; stream-ordered before g2)
  C12 ca;
  ca.src[0]  = W_forget;             // F1  (rows 0:256   <- query_res)
  ca.src[1]  = W_forget + 256 * 256; // F2  (rows 256:512 <- hidden)
  ca.src[2]  = W_forget + 768 * 256; // F4  (rows 768:1024<- query)
  ca.src[3]  = W_hid;                // H1
  ca.src[4]  = W_hid + 256 * 256;    // H2  (<- forget*hidden)
  ca.src[5]  = W_hid + 768 * 256;    // H4
  ca.src[6]  = W_query;              // Q1  (rows 0:256 <- hidden)
  ca.src[7]  = W_query + 512 * 256;  // Q3  (rows 512:768 <- query)
  ca.src[8]  = tmpA;                 // A   (replaces O1)
  ca.src[9]  = tmpB;                 // B   (replaces O3)
  ca.src[10] = W_srep;               // SR
  ca.src[11] = W_skey;               // SK
  cvt_panels<<<dim3(256, 12), 256, 0, stream>>>(ca, panels);

  // 3) per-(b,i) precomputes (overwrite tmp area safely now)
  G4 g1;
  for (int j = 0; j < 4; ++j) { g1.Bm[j] = W_self; g1.bias[j] = b_self; g1.C[j] = rep; }
  gemm16<<<dim3(128, 1), 256, 0, stream>>>(nodes, g1);

  G4 g2;
  g2.Bm[0] = W_forget + 512 * 256; g2.bias[0] = b_forget; g2.C[0] = pf;
  g2.Bm[1] = W_hid + 512 * 256;    g2.bias[1] = b_hid;    g2.C[1] = ph;
  g2.Bm[2] = W_query + 256 * 256;  g2.bias[2] = b_query;  g2.C[2] = pq;
  g2.Bm[3] = W_out + 256 * 256;    g2.bias[3] = b_out;    g2.C[3] = po;
  gemm16<<<dim3(128, 4), 256, 0, stream>>>(rep, g2);

  gemmD<<<128, 256, 0, stream>>>(pq, O3, po, po);    // poO = pq@O3 + po

  dagsage_main<<<32, 512, 0, stream>>>(adj, b_srep, b_skey,
                                       pf, ph, pq, po, panels, out);
}